// Round 14
// baseline (322.668 us; speedup 1.0000x reference)
//
#include <hip/hip_runtime.h>
#include <math.h>

// ---------------------------------------------------------------------------
// S5 dual (fwd+bwd) SSM:  B=4, L=4096, H=1024, P=256
// Pipeline (5 launches):
//   cast_prep: x fp32->bf16 (blocks 0..8191) + build W/CmT/lambda (8192..9727)
//   gemm1:   Zb[16384,1024](bf16) = xbf @ W^T   (256x256 tile, 8 waves, R12)
//   scanP:   read Zb, local scan in REGISTERS, write only chunk partials
//   scanF:   carry inline from partials (direction-aware weights), SEEDED
//            recurrence -> write bf16 xsbf. Kernel boundary = sync.
//   gemm2:   R14: SAME 256x256/8-wave/counted-vmcnt structure as gemm1.
//            Dual-K handled by bf16 STASH: kt 0..7 -> acc (fwd);
//            mid-epilogue stash=bf16(gelu(acc+Df*x)) [64 u32], acc=0;
//            kt 8..15 -> acc (bwd); out = stash + gelu(acc+Db*x).
//            Register budget: acc 128 + stash 64 + ops ~24 + addr ~25 < 256.
// R5: dbuf+__syncthreads REGRESSED. R6: 32x32x16 neutral+conflicts.
// R9: in-kernel lookback atomics disaster -> kernel-boundary sync.
// R11: counted vmcnt on 128^2 2-phase: +4us. R12: gemm1 256^2: -5us.
// R13: scanP/scanF (no Zb write-back): -1us.
// Column layout (inner 1024): c = dir*512 + 2*p + comp  (comp: 0=re, 1=im)
// LDS tiles use XOR swizzle (T2): linear global_load_lds dest, pre-swizzled
// global source column, XOR'd ds_read index (rule #21). Conflicts == 0.
// ---------------------------------------------------------------------------

typedef short bf16x8 __attribute__((ext_vector_type(8)));
typedef float f32x4 __attribute__((ext_vector_type(4)));
typedef unsigned short u16x8 __attribute__((ext_vector_type(8)));

__device__ __forceinline__ unsigned short f2bf(float f) {
  union { float f; unsigned int u; } v; v.f = f;
  unsigned int r = (v.u + 0x7FFFu + ((v.u >> 16) & 1u)) >> 16;
  return (unsigned short)r;
}
__device__ __forceinline__ float bf2f(unsigned short s) {
  union { unsigned int u; float f; } v; v.u = ((unsigned int)s) << 16;
  return v.f;
}
// tanh-form gelu via sigmoid: gelu(v) ~= v * sigmoid(1.5957691*(v+0.044715 v^3))
__device__ __forceinline__ float gelu_fast(float v) {
  const float u = 1.5957691216057308f * fmaf(0.044715f * v, v * v, v);
  return v / (1.f + __expf(-u));
}
__device__ __forceinline__ void gload16(const unsigned short* g, void* l) {
  __builtin_amdgcn_global_load_lds(
      (const __attribute__((address_space(1))) void*)g,
      (__attribute__((address_space(3))) void*)l, 16, 0, 0);
}

// --------------------- fused cast_x + prep ----------------------------------
__global__ __launch_bounds__(256) void cast_prep_kernel(
    const float* __restrict__ x, unsigned short* __restrict__ xbf,
    const float* __restrict__ flr, const float* __restrict__ fim,
    const float* __restrict__ fBr, const float* __restrict__ fBi,
    const float* __restrict__ fCr, const float* __restrict__ fCi,
    const float* __restrict__ flD,
    const float* __restrict__ blr, const float* __restrict__ bim,
    const float* __restrict__ bBr, const float* __restrict__ bBi,
    const float* __restrict__ bCr, const float* __restrict__ bCi,
    const float* __restrict__ blD,
    unsigned short* __restrict__ W, unsigned short* __restrict__ CmT,
    float4* __restrict__ lamp) {
  const int tid = threadIdx.x;
  if (blockIdx.x < 8192) {  // -------- cast path: 8 floats/thread
    const size_t i = (size_t)blockIdx.x * 256 + tid;
    const float4* xv = (const float4*)x;
    float4 a = xv[2 * i], b = xv[2 * i + 1];
    u16x8 r;
    r[0] = f2bf(a.x); r[1] = f2bf(a.y); r[2] = f2bf(a.z); r[3] = f2bf(a.w);
    r[4] = f2bf(b.x); r[5] = f2bf(b.y); r[6] = f2bf(b.z); r[7] = f2bf(b.w);
    *(u16x8*)(xbf + 8 * i) = r;
    return;
  }
  const int bid = blockIdx.x - 8192;  // -------- prep path (0..1535)
  if (bid < 512) {
    const int dir = bid >> 8, p = bid & 255;
    const float* lr_ = dir ? blr : flr;
    const float* im_ = dir ? bim : fim;
    const float* lD_ = dir ? blD : flD;
    const float* Br_ = dir ? bBr : fBr;
    const float* Bi_ = dir ? bBi : fBi;
    const float Lre = -expf(lr_[p]);
    const float Lim = im_[p];
    const float Dl = expf(lD_[p]);
    const float ar = Lre * Dl, ai = Lim * Dl;
    const float er = expf(ar);
    const float lre = er * cosf(ai), lim = er * sinf(ai);
    const float e64 = expf(64.f * ar);
    const float l64re = e64 * cosf(64.f * ai), l64im = e64 * sinf(64.f * ai);
    float sre = Lre, sim = Lim;
    if (sqrtf(Lre * Lre + Lim * Lim) < 1e-6f) { sre = 1e-6f; sim = 0.f; }
    const float den = sre * sre + sim * sim;
    const float fre = ((lre - 1.f) * sre + lim * sim) / den;
    const float fi2 = (lim * sre - (lre - 1.f) * sim) / den;
    if (tid == 0) lamp[dir * 256 + p] = make_float4(lre, lim, l64re, l64im);
    const size_t rowR = (size_t)(dir * 512 + 2 * p) * 1024;
    const size_t rowI = rowR + 1024;
    for (int h = tid; h < 1024; h += 256) {
      const float Br = Br_[p * 1024 + h], Bi = Bi_[p * 1024 + h];
      W[rowR + h] = f2bf(fre * Br - fi2 * Bi);
      W[rowI + h] = f2bf(fre * Bi + fi2 * Br);
    }
  } else {
    const int h = bid - 512;
    for (int k = tid; k < 1024; k += 256) {
      const int dir = k >> 9, within = k & 511;
      const int p = within >> 1, comp = within & 1;
      const float* C = comp ? (dir ? bCi : fCi) : (dir ? bCr : fCr);
      float v = C[(size_t)h * 256 + p];
      if (comp) v = -v;
      CmT[(size_t)h * 1024 + k] = f2bf(v);
    }
  }
}

// ----------------- shared 256^2 / 8-wave stage & sync macros ----------------
// As/Bs are [2][256][64] shorts (32 KB per buffer). STAGE: 4 A-lines +
// 4 B-lines of 16B per thread, linear LDS dest, swizzled global src col.
#define G256_STAGE(BUF, KT, APTR, BPTR)                                        \
  {                                                                            \
    const int k0 = (KT) << 6;                                                  \
    _Pragma("unroll") for (int i = 0; i < 4; ++i) {                            \
      const int r = (i << 6) + tr;                                             \
      const int o = ((BUF) << 15) + (i << 13) + (tid << 4);                    \
      gload16(APTR + (size_t)(m0 + r) * 1024 + (k0 + csw), (char*)As + o);     \
      gload16(BPTR + (size_t)(n0 + r) * 1024 + (k0 + csw), (char*)Bs + o);     \
    }                                                                          \
  }

#define PIPE_PUBLISH8()                                                        \
  asm volatile("s_waitcnt vmcnt(8)" ::: "memory");                             \
  __builtin_amdgcn_sched_barrier(0);                                           \
  __builtin_amdgcn_s_barrier();                                                \
  __builtin_amdgcn_sched_barrier(0);

#define PIPE_CLOSE()                                                           \
  __builtin_amdgcn_sched_barrier(0);                                           \
  __builtin_amdgcn_s_barrier();                                                \
  __builtin_amdgcn_sched_barrier(0);

// gemm1 compute: B-frags [4][2] upfront (reused over 4 sub-phases).
#define G1_COMPUTE(BUF, ACC)                                                   \
  {                                                                            \
    const int bo = (BUF) << 14; /* element offset */                           \
    bf16x8 bF[4][2];                                                           \
    _Pragma("unroll") for (int n4 = 0; n4 < 4; ++n4)                           \
        _Pragma("unroll") for (int kk2 = 0; kk2 < 2; ++kk2) {                  \
      const int row = (wn << 6) + (n4 << 4) + fr;                              \
      bF[n4][kk2] =                                                            \
          *(const bf16x8*)&Bs[bo + row * 64 + (((kk2 << 5) + ks) ^ sw)];       \
    }                                                                          \
    _Pragma("unroll") for (int ph = 0; ph < 4; ++ph) {                         \
      bf16x8 aF[2][2];                                                         \
      _Pragma("unroll") for (int mf2 = 0; mf2 < 2; ++mf2)                      \
          _Pragma("unroll") for (int kk2 = 0; kk2 < 2; ++kk2) {                \
        const int row = (wm << 7) + (((ph << 1) + mf2) << 4) + fr;             \
        aF[mf2][kk2] =                                                         \
            *(const bf16x8*)&As[bo + row * 64 + (((kk2 << 5) + ks) ^ sw)];     \
      }                                                                        \
      __builtin_amdgcn_s_setprio(1);                                           \
      _Pragma("unroll") for (int mf2 = 0; mf2 < 2; ++mf2)                      \
          _Pragma("unroll") for (int n4 = 0; n4 < 4; ++n4)                     \
              _Pragma("unroll") for (int kk2 = 0; kk2 < 2; ++kk2)              \
                  ACC[(ph << 1) + mf2][n4] =                                   \
                      __builtin_amdgcn_mfma_f32_16x16x32_bf16(                 \
                          aF[mf2][kk2], bF[n4][kk2], ACC[(ph << 1) + mf2][n4], \
                          0, 0, 0);                                            \
      __builtin_amdgcn_s_setprio(0);                                           \
    }                                                                          \
  }

// gemm2 compute: kk-outer, B-frags [4] per kk (lower live-register peak —
// leaves room for the 64-reg bf16 stash).
#define G2_COMPUTE(BUF, ACC)                                                   \
  {                                                                            \
    const int bo = (BUF) << 14;                                                \
    _Pragma("unroll") for (int kk2 = 0; kk2 < 2; ++kk2) {                      \
      bf16x8 bF[4];                                                            \
      _Pragma("unroll") for (int n4 = 0; n4 < 4; ++n4) {                       \
        const int row = (wn << 6) + (n4 << 4) + fr;                            \
        bF[n4] =                                                               \
            *(const bf16x8*)&Bs[bo + row * 64 + (((kk2 << 5) + ks) ^ sw)];     \
      }                                                                        \
      _Pragma("unroll") for (int ph = 0; ph < 4; ++ph) {                       \
        bf16x8 aF[2];                                                          \
        _Pragma("unroll") for (int mf2 = 0; mf2 < 2; ++mf2) {                  \
          const int row = (wm << 7) + (((ph << 1) + mf2) << 4) + fr;           \
          aF[mf2] =                                                            \
              *(const bf16x8*)&As[bo + row * 64 + (((kk2 << 5) + ks) ^ sw)];   \
        }                                                                      \
        __builtin_amdgcn_s_setprio(1);                                         \
        _Pragma("unroll") for (int mf2 = 0; mf2 < 2; ++mf2)                    \
            _Pragma("unroll") for (int n4 = 0; n4 < 4; ++n4)                   \
                ACC[(ph << 1) + mf2][n4] =                                     \
                    __builtin_amdgcn_mfma_f32_16x16x32_bf16(                   \
                        aF[mf2], bF[n4], ACC[(ph << 1) + mf2][n4], 0, 0, 0);   \
        __builtin_amdgcn_s_setprio(0);                                         \
      }                                                                        \
    }                                                                          \
  }

// ------------------------------- GEMM1 (256^2, 8 waves) ---------------------
// Zb[m][c] = bf16( sum_h xbf[m][h] * W[c][h] );  M=16384, N=1024, K=1024
__global__ __launch_bounds__(512, 2) void gemm1_kernel(
    const unsigned short* __restrict__ xbf, const unsigned short* __restrict__ W,
    unsigned short* __restrict__ Zb) {
  __shared__ unsigned short As[2 * 256 * 64];  // 64 KB
  __shared__ unsigned short Bs[2 * 256 * 64];  // 64 KB
  const int tid = threadIdx.x;
  const int lane = tid & 63;
  const int w = tid >> 6;                    // 0..7
  const int wm = w >> 2, wn = w & 3;         // 2M x 4N
  const int fr = lane & 15;
  const int ks = (lane >> 4) << 3;
  const int sw = (fr & 7) << 3;              // ds_read XOR (elements)
  const int tr = tid >> 3;                   // staging row-within-64 (0..63)
  const int csw = ((tid & 7) ^ (tr & 7)) << 3;  // staging src col (elems)
  const int bsw = ((blockIdx.x & 7) << 5) + (blockIdx.x >> 3);  // XCD swizzle
  const int nt = bsw & 3, mt = bsw >> 2;     // 4 N-tiles, 64 M-tiles
  const int m0 = mt << 8, n0 = nt << 8;

  f32x4 acc[8][4] = {};

  G256_STAGE(0, 0, xbf, W);
  int cur = 0;
  for (int kt = 0; kt < 15; ++kt) {
    G256_STAGE(cur ^ 1, kt + 1, xbf, W);   // next tile: stays in flight
    PIPE_PUBLISH8();
    G1_COMPUTE(cur, acc);
    PIPE_CLOSE();
    cur ^= 1;
  }
  __syncthreads();                         // final tile: full drain ok here
  G1_COMPUTE(cur, acc);

  const int rb = (lane >> 4) << 2;
#pragma unroll
  for (int mf = 0; mf < 8; ++mf)
#pragma unroll
    for (int n4 = 0; n4 < 4; ++n4) {
      const size_t gn = n0 + (wn << 6) + (n4 << 4) + fr;
#pragma unroll
      for (int r = 0; r < 4; ++r) {
        const size_t gm = m0 + (wm << 7) + (mf << 4) + rb + r;
        Zb[gm * 1024 + gn] = f2bf(acc[mf][n4][r]);
      }
    }
}

// ------------------------------- scanP --------------------------------------
// Zb viewed as u32 pairs: Zp[m][512], col = dir*256 + p, packed (re, im) bf16.
// Block = s*64 + k (s = b*2+dir). Local scan in REGISTERS (no write-back);
// emit only the chunk-final state to part[s][k][p].
__global__ __launch_bounds__(256) void scanP_kernel(
    const unsigned int* __restrict__ Zp, const float4* __restrict__ lamp,
    float2* __restrict__ part) {
  const int p = threadIdx.x;
  const int k = blockIdx.x & 63;
  const int s = blockIdx.x >> 6;
  const int dir = s & 1, b = s >> 1;
  const float4 lp = lamp[dir * 256 + p];
  const float lre = lp.x, lim = lp.y;
  const size_t col = (size_t)dir * 256 + p;
  const size_t mbase = (size_t)b * 4096 + (size_t)k * 64;
  float sre = 0.f, sim = 0.f;
  if (dir == 0) {
    for (int i = 0; i < 64; ++i) {
      const unsigned int u = Zp[(mbase + i) * 512 + col];
      const float nr = fmaf(lre, sre, fmaf(-lim, sim, bf2f((unsigned short)u)));
      const float ni = fmaf(lre, sim, fmaf(lim, sre, bf2f((unsigned short)(u >> 16))));
      sre = nr; sim = ni;
    }
  } else {
    for (int i = 63; i >= 0; --i) {
      const unsigned int u = Zp[(mbase + i) * 512 + col];
      const float nr = fmaf(lre, sre, fmaf(-lim, sim, bf2f((unsigned short)u)));
      const float ni = fmaf(lre, sim, fmaf(lim, sre, bf2f((unsigned short)(u >> 16))));
      sre = nr; sim = ni;
    }
  }
  part[(size_t)(s * 64 + k) * 256 + p] = make_float2(sre, sim);
}

// ------------------------------- scanF --------------------------------------
// Carry inline from partials (direction-aware weights), then SEEDED
// recurrence over the chunk: s_{-1} = C;  s_i = lambda*s_{i-1} + u_i;
// write bf16-packed xs. (== loc_i + lambda^(i+1) C algebraically.)
__global__ __launch_bounds__(256) void scanF_kernel(
    const unsigned int* __restrict__ Zp, const float4* __restrict__ lamp,
    const float2* __restrict__ part, unsigned int* __restrict__ xsbf) {
  const int p = threadIdx.x;
  const int k = blockIdx.x & 63;
  const int s = blockIdx.x >> 6;
  const int dir = s & 1, b = s >> 1;
  const float4 lp = lamp[dir * 256 + p];
  const float lre = lp.x, lim = lp.y, wr64 = lp.z, wi64 = lp.w;
  const size_t col = (size_t)dir * 256 + p;
  const size_t mbase = (size_t)b * 4096 + (size_t)k * 64;

  // exclusive carry:
  //   fwd: C = sum_{j<k} l64^(k-1-j) S_j   (j descending, w starts at 1)
  //   bwd: C = sum_{j>k} l64^(j-k-1) S_j   (j ascending,  w starts at 1)
  float cr = 0.f, ci = 0.f, wr = 1.f, wi = 0.f;
  if (dir == 0) {
    for (int j = k - 1; j >= 0; --j) {
      const float2 S = part[(size_t)(s * 64 + j) * 256 + p];
      cr = fmaf(wr, S.x, fmaf(-wi, S.y, cr));
      ci = fmaf(wr, S.y, fmaf(wi, S.x, ci));
      const float t = wr * wr64 - wi * wi64;
      wi = wr * wi64 + wi * wr64; wr = t;
    }
  } else {
    for (int j = k + 1; j < 64; ++j) {
      const float2 S = part[(size_t)(s * 64 + j) * 256 + p];
      cr = fmaf(wr, S.x, fmaf(-wi, S.y, cr));
      ci = fmaf(wr, S.y, fmaf(wi, S.x, ci));
      const float t = wr * wr64 - wi * wi64;
      wi = wr * wi64 + wi * wr64; wr = t;
    }
  }

  float sre = cr, sim = ci;  // state entering the chunk
  if (dir == 0) {
    for (int i = 0; i < 64; ++i) {
      const size_t idx = (mbase + i) * 512 + col;
      const unsigned int u = Zp[idx];
      const float nr = fmaf(lre, sre, fmaf(-lim, sim, bf2f((unsigned short)u)));
      const float ni = fmaf(lre, sim, fmaf(lim, sre, bf2f((unsigned short)(u >> 16))));
      sre = nr; sim = ni;
      xsbf[idx] = (unsigned int)f2bf(sre) | ((unsigned int)f2bf(sim) << 16);
    }
  } else {
    for (int i = 63; i >= 0; --i) {
      const size_t idx = (mbase + i) * 512 + col;
      const unsigned int u = Zp[idx];
      const float nr = fmaf(lre, sre, fmaf(-lim, sim, bf2f((unsigned short)u)));
      const float ni = fmaf(lre, sim, fmaf(lim, sre, bf2f((unsigned short)(u >> 16))));
      sre = nr; sim = ni;
      xsbf[idx] = (unsigned int)f2bf(sre) | ((unsigned int)f2bf(sim) << 16);
    }
  }
}

// ----------------- GEMM2 (R14: 256^2, 8 waves, bf16 stash) ------------------
// out = gelu(accf + Df*x) + gelu(accb + Db*x);  accf: kt 0..7, accb: kt 8..15.
// Mid-kernel: stash = packed bf16 gelu-fwd; acc reused for bwd half.
__global__ __launch_bounds__(512, 2) void gemm2_kernel(
    const unsigned short* __restrict__ A2, const unsigned short* __restrict__ CmT,
    const unsigned short* __restrict__ xbf, const float* __restrict__ Df,
    const float* __restrict__ Db, float* __restrict__ out) {
  __shared__ unsigned short As[2 * 256 * 64];  // 64 KB
  __shared__ unsigned short Bs[2 * 256 * 64];  // 64 KB
  const int tid = threadIdx.x;
  const int lane = tid & 63;
  const int w = tid >> 6;
  const int wm = w >> 2, wn = w & 3;         // 2M x 4N
  const int fr = lane & 15;
  const int ks = (lane >> 4) << 3;
  const int sw = (fr & 7) << 3;
  const int tr = tid >> 3;
  const int csw = ((tid & 7) ^ (tr & 7)) << 3;
  const int bsw = ((blockIdx.x & 7) << 5) + (blockIdx.x >> 3);  // XCD swizzle
  const int nt = bsw & 3, mt = bsw >> 2;
  const int m0 = mt << 8, n0 = nt << 8;
  const int rb = (lane >> 4) << 2;

  f32x4 acc[8][4] = {};
  unsigned int stash[8][4][2];  // bf16-packed gelu-fwd (static indexing)

  G256_STAGE(0, 0, A2, CmT);
  int cur = 0;
#pragma unroll
  for (int kt = 0; kt < 7; ++kt) {
    G256_STAGE(cur ^ 1, kt + 1, A2, CmT);
    PIPE_PUBLISH8();
    G2_COMPUTE(cur, acc);
    PIPE_CLOSE();
    cur ^= 1;
  }
  // kt = 7: compute, then fwd epilogue (stash + zero acc) before the
  // trailing barrier (pure VALU; other waves stage meanwhile).
  G256_STAGE(cur ^ 1, 8, A2, CmT);
  PIPE_PUBLISH8();
  G2_COMPUTE(cur, acc);
#pragma unroll
  for (int mf = 0; mf < 8; ++mf)
#pragma unroll
    for (int n4 = 0; n4 < 4; ++n4) {
      const size_t gn = n0 + (wn << 6) + (n4 << 4) + fr;
      const float dfv = Df[gn];
#pragma unroll
      for (int pr = 0; pr < 2; ++pr) {
        const size_t gm0 = m0 + (wm << 7) + (mf << 4) + rb + 2 * pr;
        const float x0 = bf2f(xbf[gm0 * 1024 + gn]);
        const float x1 = bf2f(xbf[(gm0 + 1) * 1024 + gn]);
        const float g0 = gelu_fast(acc[mf][n4][2 * pr] + dfv * x0);
        const float g1 = gelu_fast(acc[mf][n4][2 * pr + 1] + dfv * x1);
        stash[mf][n4][pr] =
            (unsigned int)f2bf(g0) | ((unsigned int)f2bf(g1) << 16);
      }
      acc[mf][n4] = (f32x4){0.f, 0.f, 0.f, 0.f};
    }
  PIPE_CLOSE();
  cur ^= 1;
#pragma unroll
  for (int kt = 8; kt < 15; ++kt) {
    G256_STAGE(cur ^ 1, kt + 1, A2, CmT);
    PIPE_PUBLISH8();
    G2_COMPUTE(cur, acc);
    PIPE_CLOSE();
    cur ^= 1;
  }
  __syncthreads();                         // final tile: full drain ok here
  G2_COMPUTE(cur, acc);

#pragma unroll
  for (int mf = 0; mf < 8; ++mf)
#pragma unroll
    for (int n4 = 0; n4 < 4; ++n4) {
      const size_t gn = n0 + (wn << 6) + (n4 << 4) + fr;
      const float dbv = Db[gn];
#pragma unroll
      for (int pr = 0; pr < 2; ++pr) {
        const unsigned int st = stash[mf][n4][pr];
        const size_t gm0 = m0 + (wm << 7) + (mf << 4) + rb + 2 * pr;
        const float x0 = bf2f(xbf[gm0 * 1024 + gn]);
        const float x1 = bf2f(xbf[(gm0 + 1) * 1024 + gn]);
        out[gm0 * 1024 + gn] =
            bf2f((unsigned short)st) +
            gelu_fast(acc[mf][n4][2 * pr] + dbv * x0);
        out[(gm0 + 1) * 1024 + gn] =
            bf2f((unsigned short)(st >> 16)) +
            gelu_fast(acc[mf][n4][2 * pr + 1] + dbv * x1);
      }
    }
}

// ------------------------------- launch -------------------------------------
extern "C" void kernel_launch(void* const* d_in, const int* in_sizes, int n_in,
                              void* d_out, int out_size, void* d_ws, size_t ws_size,
                              hipStream_t stream) {
  const float* x = (const float*)d_in[0];
  const float* flr = (const float*)d_in[1];
  const float* fim = (const float*)d_in[2];
  const float* fBr = (const float*)d_in[3];
  const float* fBi = (const float*)d_in[4];
  const float* fCr = (const float*)d_in[5];
  const float* fCi = (const float*)d_in[6];
  const float* fD  = (const float*)d_in[7];
  const float* flD = (const float*)d_in[8];
  const float* blr = (const float*)d_in[9];
  const float* bim = (const float*)d_in[10];
  const float* bBr = (const float*)d_in[11];
  const float* bBi = (const float*)d_in[12];
  const float* bCr = (const float*)d_in[13];
  const float* bCi = (const float*)d_in[14];
  const float* bD  = (const float*)d_in[15];
  const float* blD = (const float*)d_in[16];

  char* ws = (char*)d_ws;
  unsigned short* xbf  = (unsigned short*)(ws);                  // 33,554,432
  unsigned short* W    = (unsigned short*)(ws + 33554432);       //  2,097,152
  unsigned short* CmT  = (unsigned short*)(ws + 35651584);       //  2,097,152
  unsigned short* Zb   = (unsigned short*)(ws + 37748736);       // 33,554,432
  unsigned short* xsbf = (unsigned short*)(ws + 71303168);       // 33,554,432
  float4*         lamp = (float4*)(ws + 104857600);              //      8,192
  float2*         part = (float2*)(ws + 104865792);              //  1,048,576

  cast_prep_kernel<<<9728, 256, 0, stream>>>(
      x, xbf, flr, fim, fBr, fBi, fCr, fCi, flD,
      blr, bim, bBr, bBi, bCr, bCi, blD, W, CmT, lamp);
  gemm1_kernel<<<256, 512, 0, stream>>>(xbf, W, Zb);
  scanP_kernel<<<512, 256, 0, stream>>>((unsigned int*)Zb, lamp, part);
  scanF_kernel<<<512, 256, 0, stream>>>((unsigned int*)Zb, lamp, part,
                                        (unsigned int*)xsbf);
  gemm2_kernel<<<256, 512, 0, stream>>>(xsbf, CmT, xbf, fD, bD, (float*)d_out);
}

// Round 15
// 154.859 us; speedup vs baseline: 2.0836x; 2.0836x over previous
//
#include <hip/hip_runtime.h>
#include <math.h>

// ---------------------------------------------------------------------------
// S5 dual (fwd+bwd) SSM:  B=4, L=4096, H=1024, P=256
// Pipeline (6 launches):
//   cast_prep: x fp32->bf16 (blocks 0..8191) + build W/CmT/lambda (8192..9727)
//   gemm1:   Zb[16384,1024](bf16) = xbf @ W^T   (256x256 tile, 8 waves, R12)
//   scanP:   read Zb, local scan in REGISTERS, write only chunk partials
//   scanF:   carry inline from partials (direction-aware weights), SEEDED
//            recurrence -> write bf16 xsbf. Kernel boundary = sync.
//   gemm2f:  K=512 (kt 0..7), gemm1's 256^2 structure, single acc;
//            writes gf = bf16(gelu(accf + Df*x)) into Zb's buffer (dead).
//   gemm2b:  K=512 (kt 8..15), same structure; out = gf + gelu(accb + Db*x).
// R14 LESSON: mid-kernel bf16 stash (acc 128 + stash 64 live) -> allocator
// capped VGPR at 128 and SPILLED (FETCH 49->157MB, MfmaUtil 5.6%, 240us).
// Stash belongs in HBM across a kernel boundary (32MB bf16 ~ 10us, not 175).
// R5: dbuf+__syncthreads REGRESSED. R6: 32x32x16 neutral+conflicts.
// R9: in-kernel lookback atomics disaster -> kernel-boundary sync.
// R11: counted vmcnt on 128^2 2-phase: +4us. R12: gemm1 256^2: -5us.
// R13: scanP/scanF (no Zb write-back): -1us.
// Column layout (inner 1024): c = dir*512 + 2*p + comp  (comp: 0=re, 1=im)
// LDS tiles use XOR swizzle (T2): linear global_load_lds dest, pre-swizzled
// global source column, XOR'd ds_read index (rule #21). Conflicts == 0.
// ---------------------------------------------------------------------------

typedef short bf16x8 __attribute__((ext_vector_type(8)));
typedef float f32x4 __attribute__((ext_vector_type(4)));
typedef unsigned short u16x8 __attribute__((ext_vector_type(8)));

__device__ __forceinline__ unsigned short f2bf(float f) {
  union { float f; unsigned int u; } v; v.f = f;
  unsigned int r = (v.u + 0x7FFFu + ((v.u >> 16) & 1u)) >> 16;
  return (unsigned short)r;
}
__device__ __forceinline__ float bf2f(unsigned short s) {
  union { unsigned int u; float f; } v; v.u = ((unsigned int)s) << 16;
  return v.f;
}
// tanh-form gelu via sigmoid: gelu(v) ~= v * sigmoid(1.5957691*(v+0.044715 v^3))
__device__ __forceinline__ float gelu_fast(float v) {
  const float u = 1.5957691216057308f * fmaf(0.044715f * v, v * v, v);
  return v / (1.f + __expf(-u));
}
__device__ __forceinline__ void gload16(const unsigned short* g, void* l) {
  __builtin_amdgcn_global_load_lds(
      (const __attribute__((address_space(1))) void*)g,
      (__attribute__((address_space(3))) void*)l, 16, 0, 0);
}

// --------------------- fused cast_x + prep ----------------------------------
__global__ __launch_bounds__(256) void cast_prep_kernel(
    const float* __restrict__ x, unsigned short* __restrict__ xbf,
    const float* __restrict__ flr, const float* __restrict__ fim,
    const float* __restrict__ fBr, const float* __restrict__ fBi,
    const float* __restrict__ fCr, const float* __restrict__ fCi,
    const float* __restrict__ flD,
    const float* __restrict__ blr, const float* __restrict__ bim,
    const float* __restrict__ bBr, const float* __restrict__ bBi,
    const float* __restrict__ bCr, const float* __restrict__ bCi,
    const float* __restrict__ blD,
    unsigned short* __restrict__ W, unsigned short* __restrict__ CmT,
    float4* __restrict__ lamp) {
  const int tid = threadIdx.x;
  if (blockIdx.x < 8192) {  // -------- cast path: 8 floats/thread
    const size_t i = (size_t)blockIdx.x * 256 + tid;
    const float4* xv = (const float4*)x;
    float4 a = xv[2 * i], b = xv[2 * i + 1];
    u16x8 r;
    r[0] = f2bf(a.x); r[1] = f2bf(a.y); r[2] = f2bf(a.z); r[3] = f2bf(a.w);
    r[4] = f2bf(b.x); r[5] = f2bf(b.y); r[6] = f2bf(b.z); r[7] = f2bf(b.w);
    *(u16x8*)(xbf + 8 * i) = r;
    return;
  }
  const int bid = blockIdx.x - 8192;  // -------- prep path (0..1535)
  if (bid < 512) {
    const int dir = bid >> 8, p = bid & 255;
    const float* lr_ = dir ? blr : flr;
    const float* im_ = dir ? bim : fim;
    const float* lD_ = dir ? blD : flD;
    const float* Br_ = dir ? bBr : fBr;
    const float* Bi_ = dir ? bBi : fBi;
    const float Lre = -expf(lr_[p]);
    const float Lim = im_[p];
    const float Dl = expf(lD_[p]);
    const float ar = Lre * Dl, ai = Lim * Dl;
    const float er = expf(ar);
    const float lre = er * cosf(ai), lim = er * sinf(ai);
    const float e64 = expf(64.f * ar);
    const float l64re = e64 * cosf(64.f * ai), l64im = e64 * sinf(64.f * ai);
    float sre = Lre, sim = Lim;
    if (sqrtf(Lre * Lre + Lim * Lim) < 1e-6f) { sre = 1e-6f; sim = 0.f; }
    const float den = sre * sre + sim * sim;
    const float fre = ((lre - 1.f) * sre + lim * sim) / den;
    const float fi2 = (lim * sre - (lre - 1.f) * sim) / den;
    if (tid == 0) lamp[dir * 256 + p] = make_float4(lre, lim, l64re, l64im);
    const size_t rowR = (size_t)(dir * 512 + 2 * p) * 1024;
    const size_t rowI = rowR + 1024;
    for (int h = tid; h < 1024; h += 256) {
      const float Br = Br_[p * 1024 + h], Bi = Bi_[p * 1024 + h];
      W[rowR + h] = f2bf(fre * Br - fi2 * Bi);
      W[rowI + h] = f2bf(fre * Bi + fi2 * Br);
    }
  } else {
    const int h = bid - 512;
    for (int k = tid; k < 1024; k += 256) {
      const int dir = k >> 9, within = k & 511;
      const int p = within >> 1, comp = within & 1;
      const float* C = comp ? (dir ? bCi : fCi) : (dir ? bCr : fCr);
      float v = C[(size_t)h * 256 + p];
      if (comp) v = -v;
      CmT[(size_t)h * 1024 + k] = f2bf(v);
    }
  }
}

// ----------------- shared 256^2 / 8-wave stage & sync macros ----------------
// As/Bs are [2][256][64] shorts (32 KB per buffer). STAGE: 4 A-lines +
// 4 B-lines of 16B per thread, linear LDS dest, swizzled global src col.
#define G256_STAGE(BUF, KT, APTR, BPTR)                                        \
  {                                                                            \
    const int k0 = (KT) << 6;                                                  \
    _Pragma("unroll") for (int i = 0; i < 4; ++i) {                            \
      const int r = (i << 6) + tr;                                             \
      const int o = ((BUF) << 15) + (i << 13) + (tid << 4);                    \
      gload16(APTR + (size_t)(m0 + r) * 1024 + (k0 + csw), (char*)As + o);     \
      gload16(BPTR + (size_t)(n0 + r) * 1024 + (k0 + csw), (char*)Bs + o);     \
    }                                                                          \
  }

#define PIPE_PUBLISH8()                                                        \
  asm volatile("s_waitcnt vmcnt(8)" ::: "memory");                             \
  __builtin_amdgcn_sched_barrier(0);                                           \
  __builtin_amdgcn_s_barrier();                                                \
  __builtin_amdgcn_sched_barrier(0);

#define PIPE_CLOSE()                                                           \
  __builtin_amdgcn_sched_barrier(0);                                           \
  __builtin_amdgcn_s_barrier();                                                \
  __builtin_amdgcn_sched_barrier(0);

// 256^2 compute: B-frags [4][2] upfront (reused over 4 sub-phases of 16 MFMA).
#define G1_COMPUTE(BUF, ACC)                                                   \
  {                                                                            \
    const int bo = (BUF) << 14; /* element offset */                           \
    bf16x8 bF[4][2];                                                           \
    _Pragma("unroll") for (int n4 = 0; n4 < 4; ++n4)                           \
        _Pragma("unroll") for (int kk2 = 0; kk2 < 2; ++kk2) {                  \
      const int row = (wn << 6) + (n4 << 4) + fr;                              \
      bF[n4][kk2] =                                                            \
          *(const bf16x8*)&Bs[bo + row * 64 + (((kk2 << 5) + ks) ^ sw)];       \
    }                                                                          \
    _Pragma("unroll") for (int ph = 0; ph < 4; ++ph) {                         \
      bf16x8 aF[2][2];                                                         \
      _Pragma("unroll") for (int mf2 = 0; mf2 < 2; ++mf2)                      \
          _Pragma("unroll") for (int kk2 = 0; kk2 < 2; ++kk2) {                \
        const int row = (wm << 7) + (((ph << 1) + mf2) << 4) + fr;             \
        aF[mf2][kk2] =                                                         \
            *(const bf16x8*)&As[bo + row * 64 + (((kk2 << 5) + ks) ^ sw)];     \
      }                                                                        \
      __builtin_amdgcn_s_setprio(1);                                           \
      _Pragma("unroll") for (int mf2 = 0; mf2 < 2; ++mf2)                      \
          _Pragma("unroll") for (int n4 = 0; n4 < 4; ++n4)                     \
              _Pragma("unroll") for (int kk2 = 0; kk2 < 2; ++kk2)              \
                  ACC[(ph << 1) + mf2][n4] =                                   \
                      __builtin_amdgcn_mfma_f32_16x16x32_bf16(                 \
                          aF[mf2][kk2], bF[n4][kk2], ACC[(ph << 1) + mf2][n4], \
                          0, 0, 0);                                            \
      __builtin_amdgcn_s_setprio(0);                                           \
    }                                                                          \
  }

// Common geometry preamble for 256^2 kernels (512 threads).
#define G256_PREAMBLE                                                          \
  const int tid = threadIdx.x;                                                 \
  const int lane = tid & 63;                                                   \
  const int w = tid >> 6;                                                      \
  const int wm = w >> 2, wn = w & 3; /* 2M x 4N */                             \
  const int fr = lane & 15;                                                    \
  const int ks = (lane >> 4) << 3;                                             \
  const int sw = (fr & 7) << 3;                                                \
  const int tr = tid >> 3;                                                     \
  const int csw = ((tid & 7) ^ (tr & 7)) << 3;                                 \
  const int bsw = ((blockIdx.x & 7) << 5) + (blockIdx.x >> 3);                 \
  const int nt = bsw & 3, mt = bsw >> 2;                                       \
  const int m0 = mt << 8, n0 = nt << 8;                                        \
  const int rb = (lane >> 4) << 2;

// ------------------------------- GEMM1 (256^2, 8 waves) ---------------------
// Zb[m][c] = bf16( sum_h xbf[m][h] * W[c][h] );  M=16384, N=1024, K=1024
__global__ __launch_bounds__(512, 2) void gemm1_kernel(
    const unsigned short* __restrict__ xbf, const unsigned short* __restrict__ W,
    unsigned short* __restrict__ Zb) {
  __shared__ unsigned short As[2 * 256 * 64];  // 64 KB
  __shared__ unsigned short Bs[2 * 256 * 64];  // 64 KB
  G256_PREAMBLE

  f32x4 acc[8][4] = {};

  G256_STAGE(0, 0, xbf, W);
  int cur = 0;
  for (int kt = 0; kt < 15; ++kt) {
    G256_STAGE(cur ^ 1, kt + 1, xbf, W);   // next tile: stays in flight
    PIPE_PUBLISH8();
    G1_COMPUTE(cur, acc);
    PIPE_CLOSE();
    cur ^= 1;
  }
  __syncthreads();                         // final tile: full drain ok here
  G1_COMPUTE(cur, acc);

#pragma unroll
  for (int mf = 0; mf < 8; ++mf)
#pragma unroll
    for (int n4 = 0; n4 < 4; ++n4) {
      const size_t gn = n0 + (wn << 6) + (n4 << 4) + fr;
#pragma unroll
      for (int r = 0; r < 4; ++r) {
        const size_t gm = m0 + (wm << 7) + (mf << 4) + rb + r;
        Zb[gm * 1024 + gn] = f2bf(acc[mf][n4][r]);
      }
    }
}

// ------------------------------- scanP --------------------------------------
// Zb viewed as u32 pairs: Zp[m][512], col = dir*256 + p, packed (re, im) bf16.
// Block = s*64 + k (s = b*2+dir). Local scan in REGISTERS (no write-back);
// emit only the chunk-final state to part[s][k][p].
__global__ __launch_bounds__(256) void scanP_kernel(
    const unsigned int* __restrict__ Zp, const float4* __restrict__ lamp,
    float2* __restrict__ part) {
  const int p = threadIdx.x;
  const int k = blockIdx.x & 63;
  const int s = blockIdx.x >> 6;
  const int dir = s & 1, b = s >> 1;
  const float4 lp = lamp[dir * 256 + p];
  const float lre = lp.x, lim = lp.y;
  const size_t col = (size_t)dir * 256 + p;
  const size_t mbase = (size_t)b * 4096 + (size_t)k * 64;
  float sre = 0.f, sim = 0.f;
  if (dir == 0) {
    for (int i = 0; i < 64; ++i) {
      const unsigned int u = Zp[(mbase + i) * 512 + col];
      const float nr = fmaf(lre, sre, fmaf(-lim, sim, bf2f((unsigned short)u)));
      const float ni = fmaf(lre, sim, fmaf(lim, sre, bf2f((unsigned short)(u >> 16))));
      sre = nr; sim = ni;
    }
  } else {
    for (int i = 63; i >= 0; --i) {
      const unsigned int u = Zp[(mbase + i) * 512 + col];
      const float nr = fmaf(lre, sre, fmaf(-lim, sim, bf2f((unsigned short)u)));
      const float ni = fmaf(lre, sim, fmaf(lim, sre, bf2f((unsigned short)(u >> 16))));
      sre = nr; sim = ni;
    }
  }
  part[(size_t)(s * 64 + k) * 256 + p] = make_float2(sre, sim);
}

// ------------------------------- scanF --------------------------------------
// Carry inline from partials (direction-aware weights), then SEEDED
// recurrence over the chunk: s_{-1} = C;  s_i = lambda*s_{i-1} + u_i;
// write bf16-packed xs. (== loc_i + lambda^(i+1) C algebraically.)
__global__ __launch_bounds__(256) void scanF_kernel(
    const unsigned int* __restrict__ Zp, const float4* __restrict__ lamp,
    const float2* __restrict__ part, unsigned int* __restrict__ xsbf) {
  const int p = threadIdx.x;
  const int k = blockIdx.x & 63;
  const int s = blockIdx.x >> 6;
  const int dir = s & 1, b = s >> 1;
  const float4 lp = lamp[dir * 256 + p];
  const float lre = lp.x, lim = lp.y, wr64 = lp.z, wi64 = lp.w;
  const size_t col = (size_t)dir * 256 + p;
  const size_t mbase = (size_t)b * 4096 + (size_t)k * 64;

  // exclusive carry:
  //   fwd: C = sum_{j<k} l64^(k-1-j) S_j   (j descending, w starts at 1)
  //   bwd: C = sum_{j>k} l64^(j-k-1) S_j   (j ascending,  w starts at 1)
  float cr = 0.f, ci = 0.f, wr = 1.f, wi = 0.f;
  if (dir == 0) {
    for (int j = k - 1; j >= 0; --j) {
      const float2 S = part[(size_t)(s * 64 + j) * 256 + p];
      cr = fmaf(wr, S.x, fmaf(-wi, S.y, cr));
      ci = fmaf(wr, S.y, fmaf(wi, S.x, ci));
      const float t = wr * wr64 - wi * wi64;
      wi = wr * wi64 + wi * wr64; wr = t;
    }
  } else {
    for (int j = k + 1; j < 64; ++j) {
      const float2 S = part[(size_t)(s * 64 + j) * 256 + p];
      cr = fmaf(wr, S.x, fmaf(-wi, S.y, cr));
      ci = fmaf(wr, S.y, fmaf(wi, S.x, ci));
      const float t = wr * wr64 - wi * wi64;
      wi = wr * wi64 + wi * wr64; wr = t;
    }
  }

  float sre = cr, sim = ci;  // state entering the chunk
  if (dir == 0) {
    for (int i = 0; i < 64; ++i) {
      const size_t idx = (mbase + i) * 512 + col;
      const unsigned int u = Zp[idx];
      const float nr = fmaf(lre, sre, fmaf(-lim, sim, bf2f((unsigned short)u)));
      const float ni = fmaf(lre, sim, fmaf(lim, sre, bf2f((unsigned short)(u >> 16))));
      sre = nr; sim = ni;
      xsbf[idx] = (unsigned int)f2bf(sre) | ((unsigned int)f2bf(sim) << 16);
    }
  } else {
    for (int i = 63; i >= 0; --i) {
      const size_t idx = (mbase + i) * 512 + col;
      const unsigned int u = Zp[idx];
      const float nr = fmaf(lre, sre, fmaf(-lim, sim, bf2f((unsigned short)u)));
      const float ni = fmaf(lre, sim, fmaf(lim, sre, bf2f((unsigned short)(u >> 16))));
      sre = nr; sim = ni;
      xsbf[idx] = (unsigned int)f2bf(sre) | ((unsigned int)f2bf(sim) << 16);
    }
  }
}

// ------------------- GEMM2f (K=512 fwd half, 256^2, 8 waves) ----------------
// gf[m][h] = bf16( gelu( sum_{k<512} A2[m][k]*CmT[h][k] + Df[h]*x[m][h] ) )
__global__ __launch_bounds__(512, 2) void gemm2f_kernel(
    const unsigned short* __restrict__ A2, const unsigned short* __restrict__ CmT,
    const unsigned short* __restrict__ xbf, const float* __restrict__ Df,
    unsigned short* __restrict__ gf) {
  __shared__ unsigned short As[2 * 256 * 64];
  __shared__ unsigned short Bs[2 * 256 * 64];
  G256_PREAMBLE

  f32x4 acc[8][4] = {};

  G256_STAGE(0, 0, A2, CmT);
  int cur = 0;
#pragma unroll
  for (int kt = 0; kt < 7; ++kt) {
    G256_STAGE(cur ^ 1, kt + 1, A2, CmT);
    PIPE_PUBLISH8();
    G1_COMPUTE(cur, acc);
    PIPE_CLOSE();
    cur ^= 1;
  }
  __syncthreads();
  G1_COMPUTE(cur, acc);

#pragma unroll
  for (int mf = 0; mf < 8; ++mf)
#pragma unroll
    for (int n4 = 0; n4 < 4; ++n4) {
      const size_t gn = n0 + (wn << 6) + (n4 << 4) + fr;
      const float dfv = Df[gn];
#pragma unroll
      for (int r = 0; r < 4; ++r) {
        const size_t gm = m0 + (wm << 7) + (mf << 4) + rb + r;
        const float xv = bf2f(xbf[gm * 1024 + gn]);
        gf[gm * 1024 + gn] = f2bf(gelu_fast(acc[mf][n4][r] + dfv * xv));
      }
    }
}

// ------------------- GEMM2b (K=512 bwd half, 256^2, 8 waves) ----------------
// out[m][h] = gf[m][h] + gelu( sum_{k>=512} A2[m][k]*CmT[h][k] + Db[h]*x )
__global__ __launch_bounds__(512, 2) void gemm2b_kernel(
    const unsigned short* __restrict__ A2, const unsigned short* __restrict__ CmT,
    const unsigned short* __restrict__ xbf, const float* __restrict__ Db,
    const unsigned short* __restrict__ gf, float* __restrict__ out) {
  __shared__ unsigned short As[2 * 256 * 64];
  __shared__ unsigned short Bs[2 * 256 * 64];
  G256_PREAMBLE

  f32x4 acc[8][4] = {};

  G256_STAGE(0, 8, A2, CmT);
  int cur = 0;
#pragma unroll
  for (int kt = 8; kt < 15; ++kt) {
    G256_STAGE(cur ^ 1, kt + 1, A2, CmT);
    PIPE_PUBLISH8();
    G1_COMPUTE(cur, acc);
    PIPE_CLOSE();
    cur ^= 1;
  }
  __syncthreads();
  G1_COMPUTE(cur, acc);

#pragma unroll
  for (int mf = 0; mf < 8; ++mf)
#pragma unroll
    for (int n4 = 0; n4 < 4; ++n4) {
      const size_t gn = n0 + (wn << 6) + (n4 << 4) + fr;
      const float dbv = Db[gn];
#pragma unroll
      for (int r = 0; r < 4; ++r) {
        const size_t gm = m0 + (wm << 7) + (mf << 4) + rb + r;
        const float xv = bf2f(xbf[gm * 1024 + gn]);
        out[gm * 1024 + gn] = bf2f(gf[gm * 1024 + gn]) +
                              gelu_fast(acc[mf][n4][r] + dbv * xv);
      }
    }
}

// ------------------------------- launch -------------------------------------
extern "C" void kernel_launch(void* const* d_in, const int* in_sizes, int n_in,
                              void* d_out, int out_size, void* d_ws, size_t ws_size,
                              hipStream_t stream) {
  const float* x = (const float*)d_in[0];
  const float* flr = (const float*)d_in[1];
  const float* fim = (const float*)d_in[2];
  const float* fBr = (const float*)d_in[3];
  const float* fBi = (const float*)d_in[4];
  const float* fCr = (const float*)d_in[5];
  const float* fCi = (const float*)d_in[6];
  const float* fD  = (const float*)d_in[7];
  const float* flD = (const float*)d_in[8];
  const float* blr = (const float*)d_in[9];
  const float* bim = (const float*)d_in[10];
  const float* bBr = (const float*)d_in[11];
  const float* bBi = (const float*)d_in[12];
  const float* bCr = (const float*)d_in[13];
  const float* bCi = (const float*)d_in[14];
  const float* bD  = (const float*)d_in[15];
  const float* blD = (const float*)d_in[16];

  char* ws = (char*)d_ws;
  unsigned short* xbf  = (unsigned short*)(ws);                  // 33,554,432
  unsigned short* W    = (unsigned short*)(ws + 33554432);       //  2,097,152
  unsigned short* CmT  = (unsigned short*)(ws + 35651584);       //  2,097,152
  unsigned short* Zb   = (unsigned short*)(ws + 37748736);       // 33,554,432
  unsigned short* xsbf = (unsigned short*)(ws + 71303168);       // 33,554,432
  float4*         lamp = (float4*)(ws + 104857600);              //      8,192
  float2*         part = (float2*)(ws + 104865792);              //  1,048,576
  unsigned short* gf   = Zb;   // Zb is dead after scanF -> reuse as gelu-fwd

  cast_prep_kernel<<<9728, 256, 0, stream>>>(
      x, xbf, flr, fim, fBr, fBi, fCr, fCi, flD,
      blr, bim, bBr, bBi, bCr, bCi, blD, W, CmT, lamp);
  gemm1_kernel<<<256, 512, 0, stream>>>(xbf, W, Zb);
  scanP_kernel<<<512, 256, 0, stream>>>((unsigned int*)Zb, lamp, part);
  scanF_kernel<<<512, 256, 0, stream>>>((unsigned int*)Zb, lamp, part,
                                        (unsigned int*)xsbf);
  gemm2f_kernel<<<256, 512, 0, stream>>>(xsbf, CmT, xbf, fD, gf);
  gemm2b_kernel<<<256, 512, 0, stream>>>(xsbf, CmT, xbf, bD, gf,
                                         (float*)d_out);
}

// Round 16
// 149.688 us; speedup vs baseline: 2.1556x; 1.0345x over previous
//
#include <hip/hip_runtime.h>
#include <math.h>

// ---------------------------------------------------------------------------
// S5 dual (fwd+bwd) SSM:  B=4, L=4096, H=1024, P=256
// Pipeline (5 launches):
//   cast_prep: x fp32->bf16 (blocks 0..8191) + build W/CmT/lambda (8192..9727)
//   gemm1:   Zb[16384,1024](bf16) = xbf @ W^T   (256x256 tile, 8 waves, R12)
//   scanP:   read Zb, local scan in REGISTERS, write only chunk partials
//            (R16: chunk=32, 1024 blocks -> 4 waves/SIMD; scans were
//             latency-bound at 2 waves/SIMD with chunk=64)
//   scanF:   carry inline from partials (direction-aware weights), SEEDED
//            recurrence -> write bf16 xsbf. Kernel boundary = sync.
//   gemm2:   128x128 tile, per-wave 64x64, DUAL acc (fwd kt 0..7 / bwd 8..15)
//            counted-vmcnt pipeline (R11). out = gelu(accf + Df*x) +
//            gelu(accb + Db*x)  (tanh-form gelu)
// R14 LESSON: mid-kernel bf16 stash -> VGPR spill (240us). R15 LESSON:
// K-split gemm2 (2 kernels, K=512 each) -> 88us vs 65.5 (pipeline fill/drain
// amortized over half the K-tiles + 64MB gf traffic). Dual-acc 128^2 stays.
// R5: dbuf+__syncthreads REGRESSED. R6: 32x32x16 neutral+conflicts.
// R9: in-kernel lookback atomics disaster -> kernel-boundary sync.
// Column layout (inner 1024): c = dir*512 + 2*p + comp  (comp: 0=re, 1=im)
// LDS tiles use XOR swizzle (T2): linear global_load_lds dest, pre-swizzled
// global source column, XOR'd ds_read index (rule #21). Conflicts == 0.
// ---------------------------------------------------------------------------

typedef short bf16x8 __attribute__((ext_vector_type(8)));
typedef float f32x4 __attribute__((ext_vector_type(4)));
typedef unsigned short u16x8 __attribute__((ext_vector_type(8)));

__device__ __forceinline__ unsigned short f2bf(float f) {
  union { float f; unsigned int u; } v; v.f = f;
  unsigned int r = (v.u + 0x7FFFu + ((v.u >> 16) & 1u)) >> 16;
  return (unsigned short)r;
}
__device__ __forceinline__ float bf2f(unsigned short s) {
  union { unsigned int u; float f; } v; v.u = ((unsigned int)s) << 16;
  return v.f;
}
// tanh-form gelu via sigmoid: gelu(v) ~= v * sigmoid(1.5957691*(v+0.044715 v^3))
__device__ __forceinline__ float gelu_fast(float v) {
  const float u = 1.5957691216057308f * fmaf(0.044715f * v, v * v, v);
  return v / (1.f + __expf(-u));
}
__device__ __forceinline__ void gload16(const unsigned short* g, void* l) {
  __builtin_amdgcn_global_load_lds(
      (const __attribute__((address_space(1))) void*)g,
      (__attribute__((address_space(3))) void*)l, 16, 0, 0);
}

// --------------------- fused cast_x + prep ----------------------------------
__global__ __launch_bounds__(256) void cast_prep_kernel(
    const float* __restrict__ x, unsigned short* __restrict__ xbf,
    const float* __restrict__ flr, const float* __restrict__ fim,
    const float* __restrict__ fBr, const float* __restrict__ fBi,
    const float* __restrict__ fCr, const float* __restrict__ fCi,
    const float* __restrict__ flD,
    const float* __restrict__ blr, const float* __restrict__ bim,
    const float* __restrict__ bBr, const float* __restrict__ bBi,
    const float* __restrict__ bCr, const float* __restrict__ bCi,
    const float* __restrict__ blD,
    unsigned short* __restrict__ W, unsigned short* __restrict__ CmT,
    float4* __restrict__ lamp) {
  const int tid = threadIdx.x;
  if (blockIdx.x < 8192) {  // -------- cast path: 8 floats/thread
    const size_t i = (size_t)blockIdx.x * 256 + tid;
    const float4* xv = (const float4*)x;
    float4 a = xv[2 * i], b = xv[2 * i + 1];
    u16x8 r;
    r[0] = f2bf(a.x); r[1] = f2bf(a.y); r[2] = f2bf(a.z); r[3] = f2bf(a.w);
    r[4] = f2bf(b.x); r[5] = f2bf(b.y); r[6] = f2bf(b.z); r[7] = f2bf(b.w);
    *(u16x8*)(xbf + 8 * i) = r;
    return;
  }
  const int bid = blockIdx.x - 8192;  // -------- prep path (0..1535)
  if (bid < 512) {
    const int dir = bid >> 8, p = bid & 255;
    const float* lr_ = dir ? blr : flr;
    const float* im_ = dir ? bim : fim;
    const float* lD_ = dir ? blD : flD;
    const float* Br_ = dir ? bBr : fBr;
    const float* Bi_ = dir ? bBi : fBi;
    const float Lre = -expf(lr_[p]);
    const float Lim = im_[p];
    const float Dl = expf(lD_[p]);
    const float ar = Lre * Dl, ai = Lim * Dl;
    const float er = expf(ar);
    const float lre = er * cosf(ai), lim = er * sinf(ai);
    const float e32 = expf(32.f * ar);   // lambda^32 (chunk length 32, R16)
    const float l32re = e32 * cosf(32.f * ai), l32im = e32 * sinf(32.f * ai);
    float sre = Lre, sim = Lim;
    if (sqrtf(Lre * Lre + Lim * Lim) < 1e-6f) { sre = 1e-6f; sim = 0.f; }
    const float den = sre * sre + sim * sim;
    const float fre = ((lre - 1.f) * sre + lim * sim) / den;
    const float fi2 = (lim * sre - (lre - 1.f) * sim) / den;
    if (tid == 0) lamp[dir * 256 + p] = make_float4(lre, lim, l32re, l32im);
    const size_t rowR = (size_t)(dir * 512 + 2 * p) * 1024;
    const size_t rowI = rowR + 1024;
    for (int h = tid; h < 1024; h += 256) {
      const float Br = Br_[p * 1024 + h], Bi = Bi_[p * 1024 + h];
      W[rowR + h] = f2bf(fre * Br - fi2 * Bi);
      W[rowI + h] = f2bf(fre * Bi + fi2 * Br);
    }
  } else {
    const int h = bid - 512;
    for (int k = tid; k < 1024; k += 256) {
      const int dir = k >> 9, within = k & 511;
      const int p = within >> 1, comp = within & 1;
      const float* C = comp ? (dir ? bCi : fCi) : (dir ? bCr : fCr);
      float v = C[(size_t)h * 256 + p];
      if (comp) v = -v;
      CmT[(size_t)h * 1024 + k] = f2bf(v);
    }
  }
}

// ----------------- shared 256^2 / 8-wave stage & sync macros ----------------
#define G256_STAGE(BUF, KT, APTR, BPTR)                                        \
  {                                                                            \
    const int k0 = (KT) << 6;                                                  \
    _Pragma("unroll") for (int i = 0; i < 4; ++i) {                            \
      const int r = (i << 6) + tr;                                             \
      const int o = ((BUF) << 15) + (i << 13) + (tid << 4);                    \
      gload16(APTR + (size_t)(m0 + r) * 1024 + (k0 + csw), (char*)As + o);     \
      gload16(BPTR + (size_t)(n0 + r) * 1024 + (k0 + csw), (char*)Bs + o);     \
    }                                                                          \
  }

#define PIPE_PUBLISH8()                                                        \
  asm volatile("s_waitcnt vmcnt(8)" ::: "memory");                             \
  __builtin_amdgcn_sched_barrier(0);                                           \
  __builtin_amdgcn_s_barrier();                                                \
  __builtin_amdgcn_sched_barrier(0);

#define PIPE_CLOSE()                                                           \
  __builtin_amdgcn_sched_barrier(0);                                           \
  __builtin_amdgcn_s_barrier();                                                \
  __builtin_amdgcn_sched_barrier(0);

// 256^2 compute: B-frags [4][2] upfront (reused over 4 sub-phases of 16 MFMA).
#define G1_COMPUTE(BUF, ACC)                                                   \
  {                                                                            \
    const int bo = (BUF) << 14; /* element offset */                           \
    bf16x8 bF[4][2];                                                           \
    _Pragma("unroll") for (int n4 = 0; n4 < 4; ++n4)                           \
        _Pragma("unroll") for (int kk2 = 0; kk2 < 2; ++kk2) {                  \
      const int row = (wn << 6) + (n4 << 4) + fr;                              \
      bF[n4][kk2] =                                                            \
          *(const bf16x8*)&Bs[bo + row * 64 + (((kk2 << 5) + ks) ^ sw)];       \
    }                                                                          \
    _Pragma("unroll") for (int ph = 0; ph < 4; ++ph) {                         \
      bf16x8 aF[2][2];                                                         \
      _Pragma("unroll") for (int mf2 = 0; mf2 < 2; ++mf2)                      \
          _Pragma("unroll") for (int kk2 = 0; kk2 < 2; ++kk2) {                \
        const int row = (wm << 7) + (((ph << 1) + mf2) << 4) + fr;             \
        aF[mf2][kk2] =                                                         \
            *(const bf16x8*)&As[bo + row * 64 + (((kk2 << 5) + ks) ^ sw)];     \
      }                                                                        \
      __builtin_amdgcn_s_setprio(1);                                           \
      _Pragma("unroll") for (int mf2 = 0; mf2 < 2; ++mf2)                      \
          _Pragma("unroll") for (int n4 = 0; n4 < 4; ++n4)                     \
              _Pragma("unroll") for (int kk2 = 0; kk2 < 2; ++kk2)              \
                  ACC[(ph << 1) + mf2][n4] =                                   \
                      __builtin_amdgcn_mfma_f32_16x16x32_bf16(                 \
                          aF[mf2][kk2], bF[n4][kk2], ACC[(ph << 1) + mf2][n4], \
                          0, 0, 0);                                            \
      __builtin_amdgcn_s_setprio(0);                                           \
    }                                                                          \
  }

// ------------------------------- GEMM1 (256^2, 8 waves) ---------------------
// Zb[m][c] = bf16( sum_h xbf[m][h] * W[c][h] );  M=16384, N=1024, K=1024
__global__ __launch_bounds__(512, 2) void gemm1_kernel(
    const unsigned short* __restrict__ xbf, const unsigned short* __restrict__ W,
    unsigned short* __restrict__ Zb) {
  __shared__ unsigned short As[2 * 256 * 64];  // 64 KB
  __shared__ unsigned short Bs[2 * 256 * 64];  // 64 KB
  const int tid = threadIdx.x;
  const int lane = tid & 63;
  const int w = tid >> 6;                    // 0..7
  const int wm = w >> 2, wn = w & 3;         // 2M x 4N
  const int fr = lane & 15;
  const int ks = (lane >> 4) << 3;
  const int sw = (fr & 7) << 3;              // ds_read XOR (elements)
  const int tr = tid >> 3;                   // staging row-within-64 (0..63)
  const int csw = ((tid & 7) ^ (tr & 7)) << 3;  // staging src col (elems)
  const int bsw = ((blockIdx.x & 7) << 5) + (blockIdx.x >> 3);  // XCD swizzle
  const int nt = bsw & 3, mt = bsw >> 2;     // 4 N-tiles, 64 M-tiles
  const int m0 = mt << 8, n0 = nt << 8;

  f32x4 acc[8][4] = {};

  G256_STAGE(0, 0, xbf, W);
  int cur = 0;
  for (int kt = 0; kt < 15; ++kt) {
    G256_STAGE(cur ^ 1, kt + 1, xbf, W);   // next tile: stays in flight
    PIPE_PUBLISH8();
    G1_COMPUTE(cur, acc);
    PIPE_CLOSE();
    cur ^= 1;
  }
  __syncthreads();                         // final tile: full drain ok here
  G1_COMPUTE(cur, acc);

  const int rb = (lane >> 4) << 2;
#pragma unroll
  for (int mf = 0; mf < 8; ++mf)
#pragma unroll
    for (int n4 = 0; n4 < 4; ++n4) {
      const size_t gn = n0 + (wn << 6) + (n4 << 4) + fr;
#pragma unroll
      for (int r = 0; r < 4; ++r) {
        const size_t gm = m0 + (wm << 7) + (mf << 4) + rb + r;
        Zb[gm * 1024 + gn] = f2bf(acc[mf][n4][r]);
      }
    }
}

// ------------------------------- scanP --------------------------------------
// Zb viewed as u32 pairs: Zp[m][512], col = dir*256 + p, packed (re, im) bf16.
// Block = s*128 + k (s = b*2+dir, chunk k of 32). Local scan in REGISTERS;
// emit only the chunk-final state to part[s][k][p].
__global__ __launch_bounds__(256) void scanP_kernel(
    const unsigned int* __restrict__ Zp, const float4* __restrict__ lamp,
    float2* __restrict__ part) {
  const int p = threadIdx.x;
  const int k = blockIdx.x & 127;
  const int s = blockIdx.x >> 7;
  const int dir = s & 1, b = s >> 1;
  const float4 lp = lamp[dir * 256 + p];
  const float lre = lp.x, lim = lp.y;
  const size_t col = (size_t)dir * 256 + p;
  const size_t mbase = (size_t)b * 4096 + (size_t)k * 32;
  float sre = 0.f, sim = 0.f;
  if (dir == 0) {
    for (int i = 0; i < 32; ++i) {
      const unsigned int u = Zp[(mbase + i) * 512 + col];
      const float nr = fmaf(lre, sre, fmaf(-lim, sim, bf2f((unsigned short)u)));
      const float ni = fmaf(lre, sim, fmaf(lim, sre, bf2f((unsigned short)(u >> 16))));
      sre = nr; sim = ni;
    }
  } else {
    for (int i = 31; i >= 0; --i) {
      const unsigned int u = Zp[(mbase + i) * 512 + col];
      const float nr = fmaf(lre, sre, fmaf(-lim, sim, bf2f((unsigned short)u)));
      const float ni = fmaf(lre, sim, fmaf(lim, sre, bf2f((unsigned short)(u >> 16))));
      sre = nr; sim = ni;
    }
  }
  part[(size_t)(s * 128 + k) * 256 + p] = make_float2(sre, sim);
}

// ------------------------------- scanF --------------------------------------
// Carry inline from partials (direction-aware weights with lambda^32), then
// SEEDED recurrence over the 32-chunk: s_{-1}=C; s_i = lambda*s_{i-1} + u_i.
__global__ __launch_bounds__(256) void scanF_kernel(
    const unsigned int* __restrict__ Zp, const float4* __restrict__ lamp,
    const float2* __restrict__ part, unsigned int* __restrict__ xsbf) {
  const int p = threadIdx.x;
  const int k = blockIdx.x & 127;
  const int s = blockIdx.x >> 7;
  const int dir = s & 1, b = s >> 1;
  const float4 lp = lamp[dir * 256 + p];
  const float lre = lp.x, lim = lp.y, wr32 = lp.z, wi32 = lp.w;
  const size_t col = (size_t)dir * 256 + p;
  const size_t mbase = (size_t)b * 4096 + (size_t)k * 32;

  // exclusive carry:
  //   fwd: C = sum_{j<k} l32^(k-1-j) S_j   (j descending, w starts at 1)
  //   bwd: C = sum_{j>k} l32^(j-k-1) S_j   (j ascending,  w starts at 1)
  float cr = 0.f, ci = 0.f, wr = 1.f, wi = 0.f;
  if (dir == 0) {
    for (int j = k - 1; j >= 0; --j) {
      const float2 S = part[(size_t)(s * 128 + j) * 256 + p];
      cr = fmaf(wr, S.x, fmaf(-wi, S.y, cr));
      ci = fmaf(wr, S.y, fmaf(wi, S.x, ci));
      const float t = wr * wr32 - wi * wi32;
      wi = wr * wi32 + wi * wr32; wr = t;
    }
  } else {
    for (int j = k + 1; j < 128; ++j) {
      const float2 S = part[(size_t)(s * 128 + j) * 256 + p];
      cr = fmaf(wr, S.x, fmaf(-wi, S.y, cr));
      ci = fmaf(wr, S.y, fmaf(wi, S.x, ci));
      const float t = wr * wr32 - wi * wi32;
      wi = wr * wi32 + wi * wr32; wr = t;
    }
  }

  float sre = cr, sim = ci;  // state entering the chunk
  if (dir == 0) {
    for (int i = 0; i < 32; ++i) {
      const size_t idx = (mbase + i) * 512 + col;
      const unsigned int u = Zp[idx];
      const float nr = fmaf(lre, sre, fmaf(-lim, sim, bf2f((unsigned short)u)));
      const float ni = fmaf(lre, sim, fmaf(lim, sre, bf2f((unsigned short)(u >> 16))));
      sre = nr; sim = ni;
      xsbf[idx] = (unsigned int)f2bf(sre) | ((unsigned int)f2bf(sim) << 16);
    }
  } else {
    for (int i = 31; i >= 0; --i) {
      const size_t idx = (mbase + i) * 512 + col;
      const unsigned int u = Zp[idx];
      const float nr = fmaf(lre, sre, fmaf(-lim, sim, bf2f((unsigned short)u)));
      const float ni = fmaf(lre, sim, fmaf(lim, sre, bf2f((unsigned short)(u >> 16))));
      sre = nr; sim = ni;
      xsbf[idx] = (unsigned int)f2bf(sre) | ((unsigned int)f2bf(sim) << 16);
    }
  }
}

// ------------------- GEMM2 (R13/R11 structure: 128^2, dual acc) --------------
#define GEMM_STAGE(BUF, KT, APTR, BPTR)                                        \
  {                                                                            \
    const int k0 = (KT) << 6;                                                  \
    _Pragma("unroll") for (int i = 0; i < 4; ++i) {                            \
      const int r = (i << 5) + tr;                                             \
      const int o = ((BUF) << 14) + (i << 12) + (tid << 4);                    \
      gload16(APTR + (size_t)(m0 + r) * 1024 + (k0 + csw), (char*)As + o);     \
      gload16(BPTR + (size_t)(n0 + r) * 1024 + (k0 + csw), (char*)Bs + o);     \
    }                                                                          \
  }

#define GEMM_COMPUTE(BUF, ACC)                                                 \
  {                                                                            \
    const int bo = (BUF) << 13; /* element offset within As/Bs */              \
    _Pragma("unroll") for (int kk = 0; kk < 64; kk += 32) {                    \
      bf16x8 af[4], bf_[4];                                                    \
      _Pragma("unroll") for (int m4 = 0; m4 < 4; ++m4) {                       \
        const int row = (wm << 6) + (m4 << 4) + fr;                            \
        af[m4] = *(const bf16x8*)&As[bo + row * 64 + ((kk + ks) ^ sw)];        \
      }                                                                        \
      _Pragma("unroll") for (int n4 = 0; n4 < 4; ++n4) {                       \
        const int row = (wn << 6) + (n4 << 4) + fr;                            \
        bf_[n4] = *(const bf16x8*)&Bs[bo + row * 64 + ((kk + ks) ^ sw)];       \
      }                                                                        \
      _Pragma("unroll") for (int m4 = 0; m4 < 4; ++m4)                         \
          _Pragma("unroll") for (int n4 = 0; n4 < 4; ++n4)                     \
              ACC[m4][n4] = __builtin_amdgcn_mfma_f32_16x16x32_bf16(           \
                  af[m4], bf_[n4], ACC[m4][n4], 0, 0, 0);                      \
    }                                                                          \
  }

__global__ __launch_bounds__(256, 2) void gemm2_kernel(
    const unsigned short* __restrict__ A2, const unsigned short* __restrict__ CmT,
    const unsigned short* __restrict__ xbf, const float* __restrict__ Df,
    const float* __restrict__ Db, float* __restrict__ out) {
  __shared__ unsigned short As[2 * 128 * 64];
  __shared__ unsigned short Bs[2 * 128 * 64];
  const int tid = threadIdx.x;
  const int lane = tid & 63;
  const int w = tid >> 6;
  const int wm = w >> 1, wn = w & 1;
  const int fr = lane & 15;
  const int ks = (lane >> 4) << 3;
  const int sw = (fr & 7) << 3;
  const int tr = tid >> 3;
  const int csw = ((tid & 7) ^ (tr & 7)) << 3;
  const int bsw = ((blockIdx.x & 7) << 7) + (blockIdx.x >> 3);  // XCD swizzle
  const int nt = bsw & 7, mt = bsw >> 3;
  const int m0 = mt << 7, n0 = nt << 7;

  f32x4 accf[4][4] = {};
  f32x4 accb[4][4] = {};

  GEMM_STAGE(0, 0, A2, CmT);
  int cur = 0;
#pragma unroll
  for (int kt = 0; kt < 8; ++kt) {
    GEMM_STAGE(cur ^ 1, kt + 1, A2, CmT);
    PIPE_PUBLISH8();
    GEMM_COMPUTE(cur, accf);
    PIPE_CLOSE();
    cur ^= 1;
  }
#pragma unroll
  for (int kt = 8; kt < 15; ++kt) {
    GEMM_STAGE(cur ^ 1, kt + 1, A2, CmT);
    PIPE_PUBLISH8();
    GEMM_COMPUTE(cur, accb);
    PIPE_CLOSE();
    cur ^= 1;
  }
  __syncthreads();                         // final tile: full drain ok here
  GEMM_COMPUTE(cur, accb);

  const int rb = (lane >> 4) << 2;
#pragma unroll
  for (int n4 = 0; n4 < 4; ++n4) {
    const size_t gn = n0 + (wn << 6) + (n4 << 4) + fr;
    const float dfv = Df[gn], dbv = Db[gn];
#pragma unroll
    for (int m4 = 0; m4 < 4; ++m4) {
#pragma unroll
      for (int r = 0; r < 4; ++r) {
        const size_t gm = m0 + (wm << 6) + (m4 << 4) + rb + r;
        const float xv = bf2f(xbf[gm * 1024 + gn]);
        out[gm * 1024 + gn] = gelu_fast(accf[m4][n4][r] + dfv * xv) +
                              gelu_fast(accb[m4][n4][r] + dbv * xv);
      }
    }
  }
}

// ------------------------------- launch -------------------------------------
extern "C" void kernel_launch(void* const* d_in, const int* in_sizes, int n_in,
                              void* d_out, int out_size, void* d_ws, size_t ws_size,
                              hipStream_t stream) {
  const float* x = (const float*)d_in[0];
  const float* flr = (const float*)d_in[1];
  const float* fim = (const float*)d_in[2];
  const float* fBr = (const float*)d_in[3];
  const float* fBi = (const float*)d_in[4];
  const float* fCr = (const float*)d_in[5];
  const float* fCi = (const float*)d_in[6];
  const float* fD  = (const float*)d_in[7];
  const float* flD = (const float*)d_in[8];
  const float* blr = (const float*)d_in[9];
  const float* bim = (const float*)d_in[10];
  const float* bBr = (const float*)d_in[11];
  const float* bBi = (const float*)d_in[12];
  const float* bCr = (const float*)d_in[13];
  const float* bCi = (const float*)d_in[14];
  const float* bD  = (const float*)d_in[15];
  const float* blD = (const float*)d_in[16];

  char* ws = (char*)d_ws;
  unsigned short* xbf  = (unsigned short*)(ws);                  // 33,554,432
  unsigned short* W    = (unsigned short*)(ws + 33554432);       //  2,097,152
  unsigned short* CmT  = (unsigned short*)(ws + 35651584);       //  2,097,152
  unsigned short* Zb   = (unsigned short*)(ws + 37748736);       // 33,554,432
  unsigned short* xsbf = (unsigned short*)(ws + 71303168);       // 33,554,432
  float4*         lamp = (float4*)(ws + 104857600);              //      8,192
  float2*         part = (float2*)(ws + 104865792);              //  2,097,152

  cast_prep_kernel<<<9728, 256, 0, stream>>>(
      x, xbf, flr, fim, fBr, fBi, fCr, fCi, flD,
      blr, bim, bBr, bBi, bCr, bCi, blD, W, CmT, lamp);
  gemm1_kernel<<<256, 512, 0, stream>>>(xbf, W, Zb);
  scanP_kernel<<<1024, 256, 0, stream>>>((unsigned int*)Zb, lamp, part);
  scanF_kernel<<<1024, 256, 0, stream>>>((unsigned int*)Zb, lamp, part,
                                         (unsigned int*)xsbf);
  gemm2_kernel<<<1024, 256, 0, stream>>>(xsbf, CmT, xbf, fD, bD, (float*)d_out);
}

// Round 17
// 147.583 us; speedup vs baseline: 2.1863x; 1.0143x over previous
//
#include <hip/hip_runtime.h>
#include <math.h>

// ---------------------------------------------------------------------------
// S5 dual (fwd+bwd) SSM:  B=4, L=4096, H=1024, P=256
// Pipeline (5 launches):
//   cast_prep: x fp32->bf16 (blocks 0..8191) + build W/CmT/lambda (8192..9727)
//   gemm1:   Zb[16384,1024](bf16) = xbf @ W^T   (256x256 tile, 8 waves)
//   scanP:   read Zb, local scan in REGISTERS, write only chunk partials
//            (chunk=64 -- R16's chunk=32 REGRESSED +4.6us)
//   scanF:   carry inline from partials (direction-aware weights), SEEDED
//            recurrence -> write bf16 xsbf. Kernel boundary = sync.
//   gemm2:   128x128 tile, per-wave 64x64, DUAL acc (fwd kt 0..7 / bwd 8..15)
// R17: T3 PHASE-LOCKED compute in both GEMMs: each MFMA quadrant/kk-phase is
//   {ds_read; s_barrier; lgkmcnt(0); setprio(1); MFMA x16; setprio(0);
//    s_barrier} -- phase-locks the 2 waves/SIMD into alternating mem/MFMA
//   roles (m218b mechanism). Staging stays counted-vmcnt (R11/R12): all 8
//   gload16 issued before vmcnt(8) -> next tile's loads fly across compute.
//   Hazards: barriers unconditional; tile's trailing phase barrier closes the
//   buffer-overwrite window; sched_barrier(0) after each asm wait (rule #18).
// R14: reg-stash spilled (240us). R15: K-split gemm2 88us vs 65.5. R16:
// chunk=32 scans +4.6us. R5: dbuf+syncthreads regressed. R6: 32x32 neutral
// (LDS bytes/FLOP is tile-geometry-invariant). R9: in-kernel lookback = L2
// fence disaster.
// Column layout (inner 1024): c = dir*512 + 2*p + comp  (comp: 0=re, 1=im)
// LDS tiles use XOR swizzle (T2): linear global_load_lds dest, pre-swizzled
// global source column, XOR'd ds_read index (rule #21). Conflicts == 0.
// ---------------------------------------------------------------------------

typedef short bf16x8 __attribute__((ext_vector_type(8)));
typedef float f32x4 __attribute__((ext_vector_type(4)));
typedef unsigned short u16x8 __attribute__((ext_vector_type(8)));

__device__ __forceinline__ unsigned short f2bf(float f) {
  union { float f; unsigned int u; } v; v.f = f;
  unsigned int r = (v.u + 0x7FFFu + ((v.u >> 16) & 1u)) >> 16;
  return (unsigned short)r;
}
__device__ __forceinline__ float bf2f(unsigned short s) {
  union { unsigned int u; float f; } v; v.u = ((unsigned int)s) << 16;
  return v.f;
}
// tanh-form gelu via sigmoid: gelu(v) ~= v * sigmoid(1.5957691*(v+0.044715 v^3))
__device__ __forceinline__ float gelu_fast(float v) {
  const float u = 1.5957691216057308f * fmaf(0.044715f * v, v * v, v);
  return v / (1.f + __expf(-u));
}
__device__ __forceinline__ void gload16(const unsigned short* g, void* l) {
  __builtin_amdgcn_global_load_lds(
      (const __attribute__((address_space(1))) void*)g,
      (__attribute__((address_space(3))) void*)l, 16, 0, 0);
}

// --------------------- fused cast_x + prep ----------------------------------
__global__ __launch_bounds__(256) void cast_prep_kernel(
    const float* __restrict__ x, unsigned short* __restrict__ xbf,
    const float* __restrict__ flr, const float* __restrict__ fim,
    const float* __restrict__ fBr, const float* __restrict__ fBi,
    const float* __restrict__ fCr, const float* __restrict__ fCi,
    const float* __restrict__ flD,
    const float* __restrict__ blr, const float* __restrict__ bim,
    const float* __restrict__ bBr, const float* __restrict__ bBi,
    const float* __restrict__ bCr, const float* __restrict__ bCi,
    const float* __restrict__ blD,
    unsigned short* __restrict__ W, unsigned short* __restrict__ CmT,
    float4* __restrict__ lamp) {
  const int tid = threadIdx.x;
  if (blockIdx.x < 8192) {  // -------- cast path: 8 floats/thread
    const size_t i = (size_t)blockIdx.x * 256 + tid;
    const float4* xv = (const float4*)x;
    float4 a = xv[2 * i], b = xv[2 * i + 1];
    u16x8 r;
    r[0] = f2bf(a.x); r[1] = f2bf(a.y); r[2] = f2bf(a.z); r[3] = f2bf(a.w);
    r[4] = f2bf(b.x); r[5] = f2bf(b.y); r[6] = f2bf(b.z); r[7] = f2bf(b.w);
    *(u16x8*)(xbf + 8 * i) = r;
    return;
  }
  const int bid = blockIdx.x - 8192;  // -------- prep path (0..1535)
  if (bid < 512) {
    const int dir = bid >> 8, p = bid & 255;
    const float* lr_ = dir ? blr : flr;
    const float* im_ = dir ? bim : fim;
    const float* lD_ = dir ? blD : flD;
    const float* Br_ = dir ? bBr : fBr;
    const float* Bi_ = dir ? bBi : fBi;
    const float Lre = -expf(lr_[p]);
    const float Lim = im_[p];
    const float Dl = expf(lD_[p]);
    const float ar = Lre * Dl, ai = Lim * Dl;
    const float er = expf(ar);
    const float lre = er * cosf(ai), lim = er * sinf(ai);
    const float e64 = expf(64.f * ar);
    const float l64re = e64 * cosf(64.f * ai), l64im = e64 * sinf(64.f * ai);
    float sre = Lre, sim = Lim;
    if (sqrtf(Lre * Lre + Lim * Lim) < 1e-6f) { sre = 1e-6f; sim = 0.f; }
    const float den = sre * sre + sim * sim;
    const float fre = ((lre - 1.f) * sre + lim * sim) / den;
    const float fi2 = (lim * sre - (lre - 1.f) * sim) / den;
    if (tid == 0) lamp[dir * 256 + p] = make_float4(lre, lim, l64re, l64im);
    const size_t rowR = (size_t)(dir * 512 + 2 * p) * 1024;
    const size_t rowI = rowR + 1024;
    for (int h = tid; h < 1024; h += 256) {
      const float Br = Br_[p * 1024 + h], Bi = Bi_[p * 1024 + h];
      W[rowR + h] = f2bf(fre * Br - fi2 * Bi);
      W[rowI + h] = f2bf(fre * Bi + fi2 * Br);
    }
  } else {
    const int h = bid - 512;
    for (int k = tid; k < 1024; k += 256) {
      const int dir = k >> 9, within = k & 511;
      const int p = within >> 1, comp = within & 1;
      const float* C = comp ? (dir ? bCi : fCi) : (dir ? bCr : fCr);
      float v = C[(size_t)h * 256 + p];
      if (comp) v = -v;
      CmT[(size_t)h * 1024 + k] = f2bf(v);
    }
  }
}

// ----------------- shared stage & sync macros --------------------------------
#define G256_STAGE(BUF, KT, APTR, BPTR)                                        \
  {                                                                            \
    const int k0 = (KT) << 6;                                                  \
    _Pragma("unroll") for (int i = 0; i < 4; ++i) {                            \
      const int r = (i << 6) + tr;                                             \
      const int o = ((BUF) << 15) + (i << 13) + (tid << 4);                    \
      gload16(APTR + (size_t)(m0 + r) * 1024 + (k0 + csw), (char*)As + o);     \
      gload16(BPTR + (size_t)(n0 + r) * 1024 + (k0 + csw), (char*)Bs + o);     \
    }                                                                          \
  }

#define PIPE_PUBLISH8()                                                        \
  asm volatile("s_waitcnt vmcnt(8)" ::: "memory");                             \
  __builtin_amdgcn_sched_barrier(0);                                           \
  __builtin_amdgcn_s_barrier();                                                \
  __builtin_amdgcn_sched_barrier(0);

// phase tail: barrier; lgkmcnt(0); prio-wrapped MFMA cluster; barrier
#define PHASE_OPEN()                                                           \
  __builtin_amdgcn_s_barrier();                                                \
  asm volatile("s_waitcnt lgkmcnt(0)" ::: "memory");                           \
  __builtin_amdgcn_sched_barrier(0);                                           \
  __builtin_amdgcn_s_setprio(1);

#define PHASE_CLOSE()                                                          \
  __builtin_amdgcn_s_setprio(0);                                               \
  __builtin_amdgcn_sched_barrier(0);                                           \
  __builtin_amdgcn_s_barrier();

// 256^2 compute, PHASE-LOCKED: 4 quadrant-phases x {reads; bar; lgkm; 16 MFMA;
// bar}. bF loaded in phase 0, reused.
#define G1_COMPUTE(BUF, ACC)                                                   \
  {                                                                            \
    const int bo = (BUF) << 14; /* element offset */                           \
    bf16x8 bF[4][2];                                                           \
    _Pragma("unroll") for (int ph = 0; ph < 4; ++ph) {                         \
      if (ph == 0) {                                                           \
        _Pragma("unroll") for (int n4 = 0; n4 < 4; ++n4)                       \
            _Pragma("unroll") for (int kk2 = 0; kk2 < 2; ++kk2) {              \
          const int row = (wn << 6) + (n4 << 4) + fr;                          \
          bF[n4][kk2] =                                                        \
              *(const bf16x8*)&Bs[bo + row * 64 + (((kk2 << 5) + ks) ^ sw)];   \
        }                                                                      \
      }                                                                        \
      bf16x8 aF[2][2];                                                         \
      _Pragma("unroll") for (int mf2 = 0; mf2 < 2; ++mf2)                      \
          _Pragma("unroll") for (int kk2 = 0; kk2 < 2; ++kk2) {                \
        const int row = (wm << 7) + (((ph << 1) + mf2) << 4) + fr;             \
        aF[mf2][kk2] =                                                         \
            *(const bf16x8*)&As[bo + row * 64 + (((kk2 << 5) + ks) ^ sw)];     \
      }                                                                        \
      PHASE_OPEN();                                                            \
      _Pragma("unroll") for (int mf2 = 0; mf2 < 2; ++mf2)                      \
          _Pragma("unroll") for (int n4 = 0; n4 < 4; ++n4)                     \
              _Pragma("unroll") for (int kk2 = 0; kk2 < 2; ++kk2)              \
                  ACC[(ph << 1) + mf2][n4] =                                   \
                      __builtin_amdgcn_mfma_f32_16x16x32_bf16(                 \
                          aF[mf2][kk2], bF[n4][kk2], ACC[(ph << 1) + mf2][n4], \
                          0, 0, 0);                                            \
      PHASE_CLOSE();                                                           \
    }                                                                          \
  }

// ------------------------------- GEMM1 (256^2, 8 waves) ---------------------
// Zb[m][c] = bf16( sum_h xbf[m][h] * W[c][h] );  M=16384, N=1024, K=1024
__global__ __launch_bounds__(512, 2) void gemm1_kernel(
    const unsigned short* __restrict__ xbf, const unsigned short* __restrict__ W,
    unsigned short* __restrict__ Zb) {
  __shared__ unsigned short As[2 * 256 * 64];  // 64 KB
  __shared__ unsigned short Bs[2 * 256 * 64];  // 64 KB
  const int tid = threadIdx.x;
  const int lane = tid & 63;
  const int w = tid >> 6;                    // 0..7
  const int wm = w >> 2, wn = w & 3;         // 2M x 4N
  const int fr = lane & 15;
  const int ks = (lane >> 4) << 3;
  const int sw = (fr & 7) << 3;              // ds_read XOR (elements)
  const int tr = tid >> 3;                   // staging row-within-64 (0..63)
  const int csw = ((tid & 7) ^ (tr & 7)) << 3;  // staging src col (elems)
  const int bsw = ((blockIdx.x & 7) << 5) + (blockIdx.x >> 3);  // XCD swizzle
  const int nt = bsw & 3, mt = bsw >> 2;     // 4 N-tiles, 64 M-tiles
  const int m0 = mt << 8, n0 = nt << 8;

  f32x4 acc[8][4] = {};

  G256_STAGE(0, 0, xbf, W);
  int cur = 0;
  for (int kt = 0; kt < 15; ++kt) {
    G256_STAGE(cur ^ 1, kt + 1, xbf, W);   // next tile: stays in flight
    PIPE_PUBLISH8();
    G1_COMPUTE(cur, acc);                  // phase-locked (trailing barrier
    cur ^= 1;                              //  closes overwrite window)
  }
  __syncthreads();                         // final tile: full drain ok here
  G1_COMPUTE(cur, acc);

  const int rb = (lane >> 4) << 2;
#pragma unroll
  for (int mf = 0; mf < 8; ++mf)
#pragma unroll
    for (int n4 = 0; n4 < 4; ++n4) {
      const size_t gn = n0 + (wn << 6) + (n4 << 4) + fr;
#pragma unroll
      for (int r = 0; r < 4; ++r) {
        const size_t gm = m0 + (wm << 7) + (mf << 4) + rb + r;
        Zb[gm * 1024 + gn] = f2bf(acc[mf][n4][r]);
      }
    }
}

// ------------------------------- scanP --------------------------------------
// Zb viewed as u32 pairs: Zp[m][512], col = dir*256 + p, packed (re, im) bf16.
// Block = s*64 + k (s = b*2+dir). Local scan in REGISTERS (no write-back);
// emit only the chunk-final state to part[s][k][p].
__global__ __launch_bounds__(256) void scanP_kernel(
    const unsigned int* __restrict__ Zp, const float4* __restrict__ lamp,
    float2* __restrict__ part) {
  const int p = threadIdx.x;
  const int k = blockIdx.x & 63;
  const int s = blockIdx.x >> 6;
  const int dir = s & 1, b = s >> 1;
  const float4 lp = lamp[dir * 256 + p];
  const float lre = lp.x, lim = lp.y;
  const size_t col = (size_t)dir * 256 + p;
  const size_t mbase = (size_t)b * 4096 + (size_t)k * 64;
  float sre = 0.f, sim = 0.f;
  if (dir == 0) {
    for (int i = 0; i < 64; ++i) {
      const unsigned int u = Zp[(mbase + i) * 512 + col];
      const float nr = fmaf(lre, sre, fmaf(-lim, sim, bf2f((unsigned short)u)));
      const float ni = fmaf(lre, sim, fmaf(lim, sre, bf2f((unsigned short)(u >> 16))));
      sre = nr; sim = ni;
    }
  } else {
    for (int i = 63; i >= 0; --i) {
      const unsigned int u = Zp[(mbase + i) * 512 + col];
      const float nr = fmaf(lre, sre, fmaf(-lim, sim, bf2f((unsigned short)u)));
      const float ni = fmaf(lre, sim, fmaf(lim, sre, bf2f((unsigned short)(u >> 16))));
      sre = nr; sim = ni;
    }
  }
  part[(size_t)(s * 64 + k) * 256 + p] = make_float2(sre, sim);
}

// ------------------------------- scanF --------------------------------------
// Carry inline from partials (direction-aware weights), then SEEDED
// recurrence over the chunk: s_{-1} = C;  s_i = lambda*s_{i-1} + u_i;
// write bf16-packed xs. (== loc_i + lambda^(i+1) C algebraically.)
__global__ __launch_bounds__(256) void scanF_kernel(
    const unsigned int* __restrict__ Zp, const float4* __restrict__ lamp,
    const float2* __restrict__ part, unsigned int* __restrict__ xsbf) {
  const int p = threadIdx.x;
  const int k = blockIdx.x & 63;
  const int s = blockIdx.x >> 6;
  const int dir = s & 1, b = s >> 1;
  const float4 lp = lamp[dir * 256 + p];
  const float lre = lp.x, lim = lp.y, wr64 = lp.z, wi64 = lp.w;
  const size_t col = (size_t)dir * 256 + p;
  const size_t mbase = (size_t)b * 4096 + (size_t)k * 64;

  // exclusive carry:
  //   fwd: C = sum_{j<k} l64^(k-1-j) S_j   (j descending, w starts at 1)
  //   bwd: C = sum_{j>k} l64^(j-k-1) S_j   (j ascending,  w starts at 1)
  float cr = 0.f, ci = 0.f, wr = 1.f, wi = 0.f;
  if (dir == 0) {
    for (int j = k - 1; j >= 0; --j) {
      const float2 S = part[(size_t)(s * 64 + j) * 256 + p];
      cr = fmaf(wr, S.x, fmaf(-wi, S.y, cr));
      ci = fmaf(wr, S.y, fmaf(wi, S.x, ci));
      const float t = wr * wr64 - wi * wi64;
      wi = wr * wi64 + wi * wr64; wr = t;
    }
  } else {
    for (int j = k + 1; j < 64; ++j) {
      const float2 S = part[(size_t)(s * 64 + j) * 256 + p];
      cr = fmaf(wr, S.x, fmaf(-wi, S.y, cr));
      ci = fmaf(wr, S.y, fmaf(wi, S.x, ci));
      const float t = wr * wr64 - wi * wi64;
      wi = wr * wi64 + wi * wr64; wr = t;
    }
  }

  float sre = cr, sim = ci;  // state entering the chunk
  if (dir == 0) {
    for (int i = 0; i < 64; ++i) {
      const size_t idx = (mbase + i) * 512 + col;
      const unsigned int u = Zp[idx];
      const float nr = fmaf(lre, sre, fmaf(-lim, sim, bf2f((unsigned short)u)));
      const float ni = fmaf(lre, sim, fmaf(lim, sre, bf2f((unsigned short)(u >> 16))));
      sre = nr; sim = ni;
      xsbf[idx] = (unsigned int)f2bf(sre) | ((unsigned int)f2bf(sim) << 16);
    }
  } else {
    for (int i = 63; i >= 0; --i) {
      const size_t idx = (mbase + i) * 512 + col;
      const unsigned int u = Zp[idx];
      const float nr = fmaf(lre, sre, fmaf(-lim, sim, bf2f((unsigned short)u)));
      const float ni = fmaf(lre, sim, fmaf(lim, sre, bf2f((unsigned short)(u >> 16))));
      sre = nr; sim = ni;
      xsbf[idx] = (unsigned int)f2bf(sre) | ((unsigned int)f2bf(sim) << 16);
    }
  }
}

// ------------------- GEMM2 (128^2, dual acc, phase-locked) -------------------
#define GEMM_STAGE(BUF, KT, APTR, BPTR)                                        \
  {                                                                            \
    const int k0 = (KT) << 6;                                                  \
    _Pragma("unroll") for (int i = 0; i < 4; ++i) {                            \
      const int r = (i << 5) + tr;                                             \
      const int o = ((BUF) << 14) + (i << 12) + (tid << 4);                    \
      gload16(APTR + (size_t)(m0 + r) * 1024 + (k0 + csw), (char*)As + o);     \
      gload16(BPTR + (size_t)(n0 + r) * 1024 + (k0 + csw), (char*)Bs + o);     \
    }                                                                          \
  }

// 2 kk-phases x {8 reads; bar; lgkm; 16 MFMA; bar}
#define GEMM_COMPUTE(BUF, ACC)                                                 \
  {                                                                            \
    const int bo = (BUF) << 13; /* element offset within As/Bs */              \
    _Pragma("unroll") for (int kk = 0; kk < 64; kk += 32) {                    \
      bf16x8 af[4], bf_[4];                                                    \
      _Pragma("unroll") for (int m4 = 0; m4 < 4; ++m4) {                       \
        const int row = (wm << 6) + (m4 << 4) + fr;                            \
        af[m4] = *(const bf16x8*)&As[bo + row * 64 + ((kk + ks) ^ sw)];        \
      }                                                                        \
      _Pragma("unroll") for (int n4 = 0; n4 < 4; ++n4) {                       \
        const int row = (wn << 6) + (n4 << 4) + fr;                            \
        bf_[n4] = *(const bf16x8*)&Bs[bo + row * 64 + ((kk + ks) ^ sw)];       \
      }                                                                        \
      PHASE_OPEN();                                                            \
      _Pragma("unroll") for (int m4 = 0; m4 < 4; ++m4)                         \
          _Pragma("unroll") for (int n4 = 0; n4 < 4; ++n4)                     \
              ACC[m4][n4] = __builtin_amdgcn_mfma_f32_16x16x32_bf16(           \
                  af[m4], bf_[n4], ACC[m4][n4], 0, 0, 0);                      \
      PHASE_CLOSE();                                                           \
    }                                                                          \
  }

__global__ __launch_bounds__(256, 2) void gemm2_kernel(
    const unsigned short* __restrict__ A2, const unsigned short* __restrict__ CmT,
    const unsigned short* __restrict__ xbf, const float* __restrict__ Df,
    const float* __restrict__ Db, float* __restrict__ out) {
  __shared__ unsigned short As[2 * 128 * 64];
  __shared__ unsigned short Bs[2 * 128 * 64];
  const int tid = threadIdx.x;
  const int lane = tid & 63;
  const int w = tid >> 6;
  const int wm = w >> 1, wn = w & 1;
  const int fr = lane & 15;
  const int ks = (lane >> 4) << 3;
  const int sw = (fr & 7) << 3;
  const int tr = tid >> 3;
  const int csw = ((tid & 7) ^ (tr & 7)) << 3;
  const int bsw = ((blockIdx.x & 7) << 7) + (blockIdx.x >> 3);  // XCD swizzle
  const int nt = bsw & 7, mt = bsw >> 3;
  const int m0 = mt << 7, n0 = nt << 7;

  f32x4 accf[4][4] = {};
  f32x4 accb[4][4] = {};

  GEMM_STAGE(0, 0, A2, CmT);
  int cur = 0;
#pragma unroll
  for (int kt = 0; kt < 8; ++kt) {
    GEMM_STAGE(cur ^ 1, kt + 1, A2, CmT);
    PIPE_PUBLISH8();
    GEMM_COMPUTE(cur, accf);               // phase-locked
    cur ^= 1;
  }
#pragma unroll
  for (int kt = 8; kt < 15; ++kt) {
    GEMM_STAGE(cur ^ 1, kt + 1, A2, CmT);
    PIPE_PUBLISH8();
    GEMM_COMPUTE(cur, accb);
    cur ^= 1;
  }
  __syncthreads();                         // final tile: full drain ok here
  GEMM_COMPUTE(cur, accb);

  const int rb = (lane >> 4) << 2;
#pragma unroll
  for (int n4 = 0; n4 < 4; ++n4) {
    const size_t gn = n0 + (wn << 6) + (n4 << 4) + fr;
    const float dfv = Df[gn], dbv = Db[gn];
#pragma unroll
    for (int m4 = 0; m4 < 4; ++m4) {
#pragma unroll
      for (int r = 0; r < 4; ++r) {
        const size_t gm = m0 + (wm << 6) + (m4 << 4) + rb + r;
        const float xv = bf2f(xbf[gm * 1024 + gn]);
        out[gm * 1024 + gn] = gelu_fast(accf[m4][n4][r] + dfv * xv) +
                              gelu_fast(accb[m4][n4][r] + dbv * xv);
      }
    }
  }
}

// ------------------------------- launch -------------------------------------
extern "C" void kernel_launch(void* const* d_in, const int* in_sizes, int n_in,
                              void* d_out, int out_size, void* d_ws, size_t ws_size,
                              hipStream_t stream) {
  const float* x = (const float*)d_in[0];
  const float* flr = (const float*)d_in[1];
  const float* fim = (const float*)d_in[2];
  const float* fBr = (const float*)d_in[3];
  const float* fBi = (const float*)d_in[4];
  const float* fCr = (const float*)d_in[5];
  const float* fCi = (const float*)d_in[6];
  const float* fD  = (const float*)d_in[7];
  const float* flD = (const float*)d_in[8];
  const float* blr = (const float*)d_in[9];
  const float* bim = (const float*)d_in[10];
  const float* bBr = (const float*)d_in[11];
  const float* bBi = (const float*)d_in[12];
  const float* bCr = (const float*)d_in[13];
  const float* bCi = (const float*)d_in[14];
  const float* bD  = (const float*)d_in[15];
  const float* blD = (const float*)d_in[16];

  char* ws = (char*)d_ws;
  unsigned short* xbf  = (unsigned short*)(ws);                  // 33,554,432
  unsigned short* W    = (unsigned short*)(ws + 33554432);       //  2,097,152
  unsigned short* CmT  = (unsigned short*)(ws + 35651584);       //  2,097,152
  unsigned short* Zb   = (unsigned short*)(ws + 37748736);       // 33,554,432
  unsigned short* xsbf = (unsigned short*)(ws + 71303168);       // 33,554,432
  float4*         lamp = (float4*)(ws + 104857600);              //      8,192
  float2*         part = (float2*)(ws + 104865792);              //  1,048,576

  cast_prep_kernel<<<9728, 256, 0, stream>>>(
      x, xbf, flr, fim, fBr, fBi, fCr, fCi, flD,
      blr, bim, bBr, bBi, bCr, bCi, blD, W, CmT, lamp);
  gemm1_kernel<<<256, 512, 0, stream>>>(xbf, W, Zb);
  scanP_kernel<<<512, 256, 0, stream>>>((unsigned int*)Zb, lamp, part);
  scanF_kernel<<<512, 256, 0, stream>>>((unsigned int*)Zb, lamp, part,
                                        (unsigned int*)xsbf);
  gemm2_kernel<<<1024, 256, 0, stream>>>(xsbf, CmT, xbf, fD, bD, (float*)d_out);
}

// Round 18
// 145.450 us; speedup vs baseline: 2.2184x; 1.0147x over previous
//
#include <hip/hip_runtime.h>
#include <math.h>

// ---------------------------------------------------------------------------
// S5 dual (fwd+bwd) SSM:  B=4, L=4096, H=1024, P=256
// Pipeline (5 launches)  [R18 = exact revert to R13, the measured optimum]:
//   cast_prep: x fp32->bf16 (blocks 0..8191) + build W/CmT/lambda (8192..9727)
//   gemm1:   Zb[16384,1024](bf16) = xbf @ W^T   (256x256 tile, 8 waves,
//            counted-vmcnt + setprio sub-phases)
//   scanP:   read Zb, local scan in REGISTERS (chunk=64), write partials only
//   scanF:   carry inline from partials (direction-aware weights), SEEDED
//            recurrence -> write bf16 xsbf. Kernel boundary = sync.
//   gemm2:   128x128 tile, per-wave 64x64, DUAL acc (fwd kt 0..7 / bwd 8..15)
//            counted-vmcnt pipeline. out = gelu(accf+Df*x)+gelu(accb+Db*x).
// Failed-attempt ledger (do not retry):
//   R5  explicit dbuf w/ __syncthreads: regressed (drain kept).
//   R6  32x32x16 MFMA: neutral + bank conflicts (LDS bytes/FLOP invariant).
//   R9  in-kernel lookback atomics: L2 fence disaster (159us scan).
//   R14 mid-kernel reg stash: allocator capped VGPR=128 -> spill, 240us.
//   R15 K-split gemm2 (2 kernels): 88us vs 65.5 (fill/drain + gf traffic).
//   R16 chunk=32 scans: +4.6us (lookback/partials overhead > ILP gain).
//   R17 coarse phase-locking: +2.5us (m196's hurt-variant; true 8-phase
//       needs 3 LDS buffers = 192KB > 160KB at this tile).
// Column layout (inner 1024): c = dir*512 + 2*p + comp  (comp: 0=re, 1=im)
// LDS tiles use XOR swizzle (T2): linear global_load_lds dest, pre-swizzled
// global source column, XOR'd ds_read index (rule #21). Conflicts == 0.
// ---------------------------------------------------------------------------

typedef short bf16x8 __attribute__((ext_vector_type(8)));
typedef float f32x4 __attribute__((ext_vector_type(4)));
typedef unsigned short u16x8 __attribute__((ext_vector_type(8)));

__device__ __forceinline__ unsigned short f2bf(float f) {
  union { float f; unsigned int u; } v; v.f = f;
  unsigned int r = (v.u + 0x7FFFu + ((v.u >> 16) & 1u)) >> 16;
  return (unsigned short)r;
}
__device__ __forceinline__ float bf2f(unsigned short s) {
  union { unsigned int u; float f; } v; v.u = ((unsigned int)s) << 16;
  return v.f;
}
// tanh-form gelu via sigmoid: gelu(v) ~= v * sigmoid(1.5957691*(v+0.044715 v^3))
__device__ __forceinline__ float gelu_fast(float v) {
  const float u = 1.5957691216057308f * fmaf(0.044715f * v, v * v, v);
  return v / (1.f + __expf(-u));
}
__device__ __forceinline__ void gload16(const unsigned short* g, void* l) {
  __builtin_amdgcn_global_load_lds(
      (const __attribute__((address_space(1))) void*)g,
      (__attribute__((address_space(3))) void*)l, 16, 0, 0);
}

// --------------------- fused cast_x + prep ----------------------------------
__global__ __launch_bounds__(256) void cast_prep_kernel(
    const float* __restrict__ x, unsigned short* __restrict__ xbf,
    const float* __restrict__ flr, const float* __restrict__ fim,
    const float* __restrict__ fBr, const float* __restrict__ fBi,
    const float* __restrict__ fCr, const float* __restrict__ fCi,
    const float* __restrict__ flD,
    const float* __restrict__ blr, const float* __restrict__ bim,
    const float* __restrict__ bBr, const float* __restrict__ bBi,
    const float* __restrict__ bCr, const float* __restrict__ bCi,
    const float* __restrict__ blD,
    unsigned short* __restrict__ W, unsigned short* __restrict__ CmT,
    float4* __restrict__ lamp) {
  const int tid = threadIdx.x;
  if (blockIdx.x < 8192) {  // -------- cast path: 8 floats/thread
    const size_t i = (size_t)blockIdx.x * 256 + tid;
    const float4* xv = (const float4*)x;
    float4 a = xv[2 * i], b = xv[2 * i + 1];
    u16x8 r;
    r[0] = f2bf(a.x); r[1] = f2bf(a.y); r[2] = f2bf(a.z); r[3] = f2bf(a.w);
    r[4] = f2bf(b.x); r[5] = f2bf(b.y); r[6] = f2bf(b.z); r[7] = f2bf(b.w);
    *(u16x8*)(xbf + 8 * i) = r;
    return;
  }
  const int bid = blockIdx.x - 8192;  // -------- prep path (0..1535)
  if (bid < 512) {
    const int dir = bid >> 8, p = bid & 255;
    const float* lr_ = dir ? blr : flr;
    const float* im_ = dir ? bim : fim;
    const float* lD_ = dir ? blD : flD;
    const float* Br_ = dir ? bBr : fBr;
    const float* Bi_ = dir ? bBi : fBi;
    const float Lre = -expf(lr_[p]);
    const float Lim = im_[p];
    const float Dl = expf(lD_[p]);
    const float ar = Lre * Dl, ai = Lim * Dl;
    const float er = expf(ar);
    const float lre = er * cosf(ai), lim = er * sinf(ai);
    const float e64 = expf(64.f * ar);
    const float l64re = e64 * cosf(64.f * ai), l64im = e64 * sinf(64.f * ai);
    float sre = Lre, sim = Lim;
    if (sqrtf(Lre * Lre + Lim * Lim) < 1e-6f) { sre = 1e-6f; sim = 0.f; }
    const float den = sre * sre + sim * sim;
    const float fre = ((lre - 1.f) * sre + lim * sim) / den;
    const float fi2 = (lim * sre - (lre - 1.f) * sim) / den;
    if (tid == 0) lamp[dir * 256 + p] = make_float4(lre, lim, l64re, l64im);
    const size_t rowR = (size_t)(dir * 512 + 2 * p) * 1024;
    const size_t rowI = rowR + 1024;
    for (int h = tid; h < 1024; h += 256) {
      const float Br = Br_[p * 1024 + h], Bi = Bi_[p * 1024 + h];
      W[rowR + h] = f2bf(fre * Br - fi2 * Bi);
      W[rowI + h] = f2bf(fre * Bi + fi2 * Br);
    }
  } else {
    const int h = bid - 512;
    for (int k = tid; k < 1024; k += 256) {
      const int dir = k >> 9, within = k & 511;
      const int p = within >> 1, comp = within & 1;
      const float* C = comp ? (dir ? bCi : fCi) : (dir ? bCr : fCr);
      float v = C[(size_t)h * 256 + p];
      if (comp) v = -v;
      CmT[(size_t)h * 1024 + k] = f2bf(v);
    }
  }
}

// ----------------- shared 256^2 / 8-wave stage & sync macros ----------------
#define G256_STAGE(BUF, KT, APTR, BPTR)                                        \
  {                                                                            \
    const int k0 = (KT) << 6;                                                  \
    _Pragma("unroll") for (int i = 0; i < 4; ++i) {                            \
      const int r = (i << 6) + tr;                                             \
      const int o = ((BUF) << 15) + (i << 13) + (tid << 4);                    \
      gload16(APTR + (size_t)(m0 + r) * 1024 + (k0 + csw), (char*)As + o);     \
      gload16(BPTR + (size_t)(n0 + r) * 1024 + (k0 + csw), (char*)Bs + o);     \
    }                                                                          \
  }

#define PIPE_PUBLISH8()                                                        \
  asm volatile("s_waitcnt vmcnt(8)" ::: "memory");                             \
  __builtin_amdgcn_sched_barrier(0);                                           \
  __builtin_amdgcn_s_barrier();                                                \
  __builtin_amdgcn_sched_barrier(0);

#define PIPE_CLOSE()                                                           \
  __builtin_amdgcn_sched_barrier(0);                                           \
  __builtin_amdgcn_s_barrier();                                                \
  __builtin_amdgcn_sched_barrier(0);

// 256^2 compute: B-frags [4][2] upfront (reused over 4 sub-phases of 16 MFMA,
// each setprio-wrapped).
#define G1_COMPUTE(BUF, ACC)                                                   \
  {                                                                            \
    const int bo = (BUF) << 14; /* element offset */                           \
    bf16x8 bF[4][2];                                                           \
    _Pragma("unroll") for (int n4 = 0; n4 < 4; ++n4)                           \
        _Pragma("unroll") for (int kk2 = 0; kk2 < 2; ++kk2) {                  \
      const int row = (wn << 6) + (n4 << 4) + fr;                              \
      bF[n4][kk2] =                                                            \
          *(const bf16x8*)&Bs[bo + row * 64 + (((kk2 << 5) + ks) ^ sw)];       \
    }                                                                          \
    _Pragma("unroll") for (int ph = 0; ph < 4; ++ph) {                         \
      bf16x8 aF[2][2];                                                         \
      _Pragma("unroll") for (int mf2 = 0; mf2 < 2; ++mf2)                      \
          _Pragma("unroll") for (int kk2 = 0; kk2 < 2; ++kk2) {                \
        const int row = (wm << 7) + (((ph << 1) + mf2) << 4) + fr;             \
        aF[mf2][kk2] =                                                         \
            *(const bf16x8*)&As[bo + row * 64 + (((kk2 << 5) + ks) ^ sw)];     \
      }                                                                        \
      __builtin_amdgcn_s_setprio(1);                                           \
      _Pragma("unroll") for (int mf2 = 0; mf2 < 2; ++mf2)                      \
          _Pragma("unroll") for (int n4 = 0; n4 < 4; ++n4)                     \
              _Pragma("unroll") for (int kk2 = 0; kk2 < 2; ++kk2)              \
                  ACC[(ph << 1) + mf2][n4] =                                   \
                      __builtin_amdgcn_mfma_f32_16x16x32_bf16(                 \
                          aF[mf2][kk2], bF[n4][kk2], ACC[(ph << 1) + mf2][n4], \
                          0, 0, 0);                                            \
      __builtin_amdgcn_s_setprio(0);                                           \
    }                                                                          \
  }

// ------------------------------- GEMM1 (256^2, 8 waves) ---------------------
// Zb[m][c] = bf16( sum_h xbf[m][h] * W[c][h] );  M=16384, N=1024, K=1024
__global__ __launch_bounds__(512, 2) void gemm1_kernel(
    const unsigned short* __restrict__ xbf, const unsigned short* __restrict__ W,
    unsigned short* __restrict__ Zb) {
  __shared__ unsigned short As[2 * 256 * 64];  // 64 KB
  __shared__ unsigned short Bs[2 * 256 * 64];  // 64 KB
  const int tid = threadIdx.x;
  const int lane = tid & 63;
  const int w = tid >> 6;                    // 0..7
  const int wm = w >> 2, wn = w & 3;         // 2M x 4N
  const int fr = lane & 15;
  const int ks = (lane >> 4) << 3;
  const int sw = (fr & 7) << 3;              // ds_read XOR (elements)
  const int tr = tid >> 3;                   // staging row-within-64 (0..63)
  const int csw = ((tid & 7) ^ (tr & 7)) << 3;  // staging src col (elems)
  const int bsw = ((blockIdx.x & 7) << 5) + (blockIdx.x >> 3);  // XCD swizzle
  const int nt = bsw & 3, mt = bsw >> 2;     // 4 N-tiles, 64 M-tiles
  const int m0 = mt << 8, n0 = nt << 8;

  f32x4 acc[8][4] = {};

  G256_STAGE(0, 0, xbf, W);
  int cur = 0;
  for (int kt = 0; kt < 15; ++kt) {
    G256_STAGE(cur ^ 1, kt + 1, xbf, W);   // next tile: stays in flight
    PIPE_PUBLISH8();
    G1_COMPUTE(cur, acc);
    PIPE_CLOSE();
    cur ^= 1;
  }
  __syncthreads();                         // final tile: full drain ok here
  G1_COMPUTE(cur, acc);

  const int rb = (lane >> 4) << 2;
#pragma unroll
  for (int mf = 0; mf < 8; ++mf)
#pragma unroll
    for (int n4 = 0; n4 < 4; ++n4) {
      const size_t gn = n0 + (wn << 6) + (n4 << 4) + fr;
#pragma unroll
      for (int r = 0; r < 4; ++r) {
        const size_t gm = m0 + (wm << 7) + (mf << 4) + rb + r;
        Zb[gm * 1024 + gn] = f2bf(acc[mf][n4][r]);
      }
    }
}

// ------------------------------- scanP --------------------------------------
// Zb viewed as u32 pairs: Zp[m][512], col = dir*256 + p, packed (re, im) bf16.
// Block = s*64 + k (s = b*2+dir). Local scan in REGISTERS (no write-back);
// emit only the chunk-final state to part[s][k][p].
__global__ __launch_bounds__(256) void scanP_kernel(
    const unsigned int* __restrict__ Zp, const float4* __restrict__ lamp,
    float2* __restrict__ part) {
  const int p = threadIdx.x;
  const int k = blockIdx.x & 63;
  const int s = blockIdx.x >> 6;
  const int dir = s & 1, b = s >> 1;
  const float4 lp = lamp[dir * 256 + p];
  const float lre = lp.x, lim = lp.y;
  const size_t col = (size_t)dir * 256 + p;
  const size_t mbase = (size_t)b * 4096 + (size_t)k * 64;
  float sre = 0.f, sim = 0.f;
  if (dir == 0) {
    for (int i = 0; i < 64; ++i) {
      const unsigned int u = Zp[(mbase + i) * 512 + col];
      const float nr = fmaf(lre, sre, fmaf(-lim, sim, bf2f((unsigned short)u)));
      const float ni = fmaf(lre, sim, fmaf(lim, sre, bf2f((unsigned short)(u >> 16))));
      sre = nr; sim = ni;
    }
  } else {
    for (int i = 63; i >= 0; --i) {
      const unsigned int u = Zp[(mbase + i) * 512 + col];
      const float nr = fmaf(lre, sre, fmaf(-lim, sim, bf2f((unsigned short)u)));
      const float ni = fmaf(lre, sim, fmaf(lim, sre, bf2f((unsigned short)(u >> 16))));
      sre = nr; sim = ni;
    }
  }
  part[(size_t)(s * 64 + k) * 256 + p] = make_float2(sre, sim);
}

// ------------------------------- scanF --------------------------------------
// Carry inline from partials (direction-aware weights), then SEEDED
// recurrence over the chunk: s_{-1} = C;  s_i = lambda*s_{i-1} + u_i;
// write bf16-packed xs. (== loc_i + lambda^(i+1) C algebraically.)
__global__ __launch_bounds__(256) void scanF_kernel(
    const unsigned int* __restrict__ Zp, const float4* __restrict__ lamp,
    const float2* __restrict__ part, unsigned int* __restrict__ xsbf) {
  const int p = threadIdx.x;
  const int k = blockIdx.x & 63;
  const int s = blockIdx.x >> 6;
  const int dir = s & 1, b = s >> 1;
  const float4 lp = lamp[dir * 256 + p];
  const float lre = lp.x, lim = lp.y, wr64 = lp.z, wi64 = lp.w;
  const size_t col = (size_t)dir * 256 + p;
  const size_t mbase = (size_t)b * 4096 + (size_t)k * 64;

  // exclusive carry:
  //   fwd: C = sum_{j<k} l64^(k-1-j) S_j   (j descending, w starts at 1)
  //   bwd: C = sum_{j>k} l64^(j-k-1) S_j   (j ascending,  w starts at 1)
  float cr = 0.f, ci = 0.f, wr = 1.f, wi = 0.f;
  if (dir == 0) {
    for (int j = k - 1; j >= 0; --j) {
      const float2 S = part[(size_t)(s * 64 + j) * 256 + p];
      cr = fmaf(wr, S.x, fmaf(-wi, S.y, cr));
      ci = fmaf(wr, S.y, fmaf(wi, S.x, ci));
      const float t = wr * wr64 - wi * wi64;
      wi = wr * wi64 + wi * wr64; wr = t;
    }
  } else {
    for (int j = k + 1; j < 64; ++j) {
      const float2 S = part[(size_t)(s * 64 + j) * 256 + p];
      cr = fmaf(wr, S.x, fmaf(-wi, S.y, cr));
      ci = fmaf(wr, S.y, fmaf(wi, S.x, ci));
      const float t = wr * wr64 - wi * wi64;
      wi = wr * wi64 + wi * wr64; wr = t;
    }
  }

  float sre = cr, sim = ci;  // state entering the chunk
  if (dir == 0) {
    for (int i = 0; i < 64; ++i) {
      const size_t idx = (mbase + i) * 512 + col;
      const unsigned int u = Zp[idx];
      const float nr = fmaf(lre, sre, fmaf(-lim, sim, bf2f((unsigned short)u)));
      const float ni = fmaf(lre, sim, fmaf(lim, sre, bf2f((unsigned short)(u >> 16))));
      sre = nr; sim = ni;
      xsbf[idx] = (unsigned int)f2bf(sre) | ((unsigned int)f2bf(sim) << 16);
    }
  } else {
    for (int i = 63; i >= 0; --i) {
      const size_t idx = (mbase + i) * 512 + col;
      const unsigned int u = Zp[idx];
      const float nr = fmaf(lre, sre, fmaf(-lim, sim, bf2f((unsigned short)u)));
      const float ni = fmaf(lre, sim, fmaf(lim, sre, bf2f((unsigned short)(u >> 16))));
      sre = nr; sim = ni;
      xsbf[idx] = (unsigned int)f2bf(sre) | ((unsigned int)f2bf(sim) << 16);
    }
  }
}

// ------------------- GEMM2 (128^2, dual acc, counted vmcnt) ------------------
#define GEMM_STAGE(BUF, KT, APTR, BPTR)                                        \
  {                                                                            \
    const int k0 = (KT) << 6;                                                  \
    _Pragma("unroll") for (int i = 0; i < 4; ++i) {                            \
      const int r = (i << 5) + tr;                                             \
      const int o = ((BUF) << 14) + (i << 12) + (tid << 4);                    \
      gload16(APTR + (size_t)(m0 + r) * 1024 + (k0 + csw), (char*)As + o);     \
      gload16(BPTR + (size_t)(n0 + r) * 1024 + (k0 + csw), (char*)Bs + o);     \
    }                                                                          \
  }

#define GEMM_COMPUTE(BUF, ACC)                                                 \
  {                                                                            \
    const int bo = (BUF) << 13; /* element offset within As/Bs */              \
    _Pragma("unroll") for (int kk = 0; kk < 64; kk += 32) {                    \
      bf16x8 af[4], bf_[4];                                                    \
      _Pragma("unroll") for (int m4 = 0; m4 < 4; ++m4) {                       \
        const int row = (wm << 6) + (m4 << 4) + fr;                            \
        af[m4] = *(const bf16x8*)&As[bo + row * 64 + ((kk + ks) ^ sw)];        \
      }                                                                        \
      _Pragma("unroll") for (int n4 = 0; n4 < 4; ++n4) {                       \
        const int row = (wn << 6) + (n4 << 4) + fr;                            \
        bf_[n4] = *(const bf16x8*)&Bs[bo + row * 64 + ((kk + ks) ^ sw)];       \
      }                                                                        \
      _Pragma("unroll") for (int m4 = 0; m4 < 4; ++m4)                         \
          _Pragma("unroll") for (int n4 = 0; n4 < 4; ++n4)                     \
              ACC[m4][n4] = __builtin_amdgcn_mfma_f32_16x16x32_bf16(           \
                  af[m4], bf_[n4], ACC[m4][n4], 0, 0, 0);                      \
    }                                                                          \
  }

__global__ __launch_bounds__(256, 2) void gemm2_kernel(
    const unsigned short* __restrict__ A2, const unsigned short* __restrict__ CmT,
    const unsigned short* __restrict__ xbf, const float* __restrict__ Df,
    const float* __restrict__ Db, float* __restrict__ out) {
  __shared__ unsigned short As[2 * 128 * 64];
  __shared__ unsigned short Bs[2 * 128 * 64];
  const int tid = threadIdx.x;
  const int lane = tid & 63;
  const int w = tid >> 6;
  const int wm = w >> 1, wn = w & 1;
  const int fr = lane & 15;
  const int ks = (lane >> 4) << 3;
  const int sw = (fr & 7) << 3;
  const int tr = tid >> 3;
  const int csw = ((tid & 7) ^ (tr & 7)) << 3;
  const int bsw = ((blockIdx.x & 7) << 7) + (blockIdx.x >> 3);  // XCD swizzle
  const int nt = bsw & 7, mt = bsw >> 3;
  const int m0 = mt << 7, n0 = nt << 7;

  f32x4 accf[4][4] = {};
  f32x4 accb[4][4] = {};

  GEMM_STAGE(0, 0, A2, CmT);
  int cur = 0;
#pragma unroll
  for (int kt = 0; kt < 8; ++kt) {
    GEMM_STAGE(cur ^ 1, kt + 1, A2, CmT);
    PIPE_PUBLISH8();
    GEMM_COMPUTE(cur, accf);
    PIPE_CLOSE();
    cur ^= 1;
  }
#pragma unroll
  for (int kt = 8; kt < 15; ++kt) {
    GEMM_STAGE(cur ^ 1, kt + 1, A2, CmT);
    PIPE_PUBLISH8();
    GEMM_COMPUTE(cur, accb);
    PIPE_CLOSE();
    cur ^= 1;
  }
  __syncthreads();                         // final tile: full drain ok here
  GEMM_COMPUTE(cur, accb);

  const int rb = (lane >> 4) << 2;
#pragma unroll
  for (int n4 = 0; n4 < 4; ++n4) {
    const size_t gn = n0 + (wn << 6) + (n4 << 4) + fr;
    const float dfv = Df[gn], dbv = Db[gn];
#pragma unroll
    for (int m4 = 0; m4 < 4; ++m4) {
#pragma unroll
      for (int r = 0; r < 4; ++r) {
        const size_t gm = m0 + (wm << 6) + (m4 << 4) + rb + r;
        const float xv = bf2f(xbf[gm * 1024 + gn]);
        out[gm * 1024 + gn] = gelu_fast(accf[m4][n4][r] + dfv * xv) +
                              gelu_fast(accb[m4][n4][r] + dbv * xv);
      }
    }
  }
}

// ------------------------------- launch -------------------------------------
extern "C" void kernel_launch(void* const* d_in, const int* in_sizes, int n_in,
                              void* d_out, int out_size, void* d_ws, size_t ws_size,
                              hipStream_t stream) {
  const float* x = (const float*)d_in[0];
  const float* flr = (const float*)d_in[1];
  const float* fim = (const float*)d_in[2];
  const float* fBr = (const float*)d_in[3];
  const float* fBi = (const float*)d_in[4];
  const float* fCr = (const float*)d_in[5];
  const float* fCi = (const float*)d_in[6];
  const float* fD  = (const float*)d_in[7];
  const float* flD = (const float*)d_in[8];
  const float* blr = (const float*)d_in[9];
  const float* bim = (const float*)d_in[10];
  const float* bBr = (const float*)d_in[11];
  const float* bBi = (const float*)d_in[12];
  const float* bCr = (const float*)d_in[13];
  const float* bCi = (const float*)d_in[14];
  const float* bD  = (const float*)d_in[15];
  const float* blD = (const float*)d_in[16];

  char* ws = (char*)d_ws;
  unsigned short* xbf  = (unsigned short*)(ws);                  // 33,554,432
  unsigned short* W    = (unsigned short*)(ws + 33554432);       //  2,097,152
  unsigned short* CmT  = (unsigned short*)(ws + 35651584);       //  2,097,152
  unsigned short* Zb   = (unsigned short*)(ws + 37748736);       // 33,554,432
  unsigned short* xsbf = (unsigned short*)(ws + 71303168);       // 33,554,432
  float4*         lamp = (float4*)(ws + 104857600);              //      8,192
  float2*         part = (float2*)(ws + 104865792);              //  1,048,576

  cast_prep_kernel<<<9728, 256, 0, stream>>>(
      x, xbf, flr, fim, fBr, fBi, fCr, fCi, flD,
      blr, bim, bBr, bBi, bCr, bCi, blD, W, CmT, lamp);
  gemm1_kernel<<<256, 512, 0, stream>>>(xbf, W, Zb);
  scanP_kernel<<<512, 256, 0, stream>>>((unsigned int*)Zb, lamp, part);
  scanF_kernel<<<512, 256, 0, stream>>>((unsigned int*)Zb, lamp, part,
                                        (unsigned int*)xsbf);
  gemm2_kernel<<<1024, 256, 0, stream>>>(xsbf, CmT, xbf, fD, bD, (float*)d_out);
}